// Round 1
// 257.317 us; speedup vs baseline: 1.0006x; 1.0006x over previous
//
#include <hip/hip_runtime.h>
#include <hip/hip_bf16.h>
#include <stdint.h>

// B=2, S=2048, D=1024, H=16, HD=64. Inputs fp32, d_out fp32 (resolved r1-r3).
// canon fp32->bf16 -> QKV GEMM (Q pre-scaled by 0.125*log2e; V transposed
// [B,H,HD,S]) -> flash attn (32x32 MFMA, kv-split 2-way, no-max exp2 softmax,
// r8: async double-buffered staging w/ raw barriers + fine vmcnt, P via
// register shfl exchange, no LDS P; r9: XOR-swizzled K/V LDS tiles to kill
// the 16-way ds_read_b128 bank conflict — pre-swizzled global source since
// global_load_lds writes linearly, same XOR on the read side) -> out-proj.
#define Bb 2
#define Ss 2048
#define Dd 1024
#define Hh 16
#define HD 64

typedef __attribute__((ext_vector_type(8))) __bf16 bf16x8;
typedef __attribute__((ext_vector_type(4))) __bf16 bf16x4;
typedef __attribute__((ext_vector_type(2))) __bf16 bf16x2;
typedef __attribute__((ext_vector_type(4))) float f32x4;
typedef __attribute__((ext_vector_type(16))) float f32x16;

#define LOG2E 1.44269504088896f
#define SCL2 (0.125f * LOG2E)

// ---- workspace layout (bf16 elements) --------------------------------------
#define HS_N   (Bb * Ss * Dd)
#define W_N    (Dd * Dd)
#define B_N    (Dd)
#define CAN_HS 0
#define CAN_WQ (CAN_HS + HS_N)
#define CAN_BQ (CAN_WQ + W_N)
#define CAN_WK (CAN_BQ + B_N)
#define CAN_BK (CAN_WK + W_N)
#define CAN_WV (CAN_BK + B_N)
#define CAN_BV (CAN_WV + W_N)
#define CAN_WO (CAN_BV + B_N)
#define CAN_BO (CAN_WO + W_N)
#define CAN_END (CAN_BO + B_N)
#define TSZ    (Bb * Hh * Ss * HD)
#define WS_ELEMS (CAN_END + 4 * TSZ)
#define WS_NEED ((size_t)WS_ELEMS * 2)

__device__ __forceinline__ void gl_lds16(const __bf16* g, __bf16* l) {
  __builtin_amdgcn_global_load_lds(
      (const __attribute__((address_space(1))) void*)g,
      (__attribute__((address_space(3))) void*)l,
      16, 0, 0);
}

__device__ __forceinline__ void cfence() { asm volatile("" ::: "memory"); }

// fp32 -> bf16 canonicalization (segment table; r4 postmortem).
__global__ void canon_kernel(const float* hs, const float* Wq, const float* bq,
                             const float* Wk, const float* bk, const float* Wv,
                             const float* bv, const float* Wo, const float* bo,
                             __bf16* __restrict__ dst) {
  const float* srcs[9] = {hs, Wq, bq, Wk, bk, Wv, bv, Wo, bo};
  const long starts[10] = {CAN_HS, CAN_WQ, CAN_BQ, CAN_WK, CAN_BK,
                           CAN_WV, CAN_BV, CAN_WO, CAN_BO, CAN_END};
  const long nchunks = CAN_END / 8;
  for (long c = blockIdx.x * blockDim.x + threadIdx.x; c < nchunks;
       c += (long)gridDim.x * blockDim.x) {
    const long i = c * 8;
    int seg = 0;
#pragma unroll
    for (int t = 1; t < 9; t++) seg += (i >= starts[t]) ? 1 : 0;
    const float* s = srcs[seg] + (i - starts[seg]);
    bf16x8 v;
#pragma unroll
    for (int e = 0; e < 8; e++) v[e] = (__bf16)s[e];
    *(bf16x8*)(dst + i) = v;
  }
}

// ---------------------------------------------------------------------------
// GEMM: C[4096, 1024(x3)] = A @ W^T + bias (bf16 in).  (unchanged from r7)
// ---------------------------------------------------------------------------
template <int MODE, typename OutT>
__global__ __launch_bounds__(256, 2) void gemm_bt(
    const __bf16* __restrict__ A,
    const __bf16* __restrict__ W0, const __bf16* __restrict__ W1,
    const __bf16* __restrict__ W2,
    const __bf16* __restrict__ b0, const __bf16* __restrict__ b1,
    const __bf16* __restrict__ b2,
    OutT* __restrict__ O0, OutT* __restrict__ O1, OutT* __restrict__ O2) {
  __shared__ __align__(16) __bf16 sA[128 * 32];
  __shared__ __align__(16) __bf16 sB[128 * 32];
  const int tid = threadIdx.x;
  const int lane = tid & 63;
  const int wid = tid >> 6;
  const int quad = lane >> 4;
  const int l15 = lane & 15;
  const int mBlock = blockIdx.x * 128;

  const __bf16* W;
  const __bf16* bias;
  OutT* Out;
  int nBlock, which = 0;
  if (MODE == 0) {
    which = blockIdx.y >> 3;  // 0:Q 1:K 2:V
    nBlock = (blockIdx.y & 7) * 128;
    W = which == 0 ? W0 : (which == 1 ? W1 : W2);
    bias = which == 0 ? b0 : (which == 1 ? b1 : b2);
    Out = which == 0 ? O0 : (which == 1 ? O1 : O2);
  } else {
    nBlock = blockIdx.y * 128;
    W = W0;
    bias = b0;
    Out = O0;
  }

  const int waveM = (wid >> 1) * 64;
  const int waveN = (wid & 1) * 64;

  f32x4 acc[4][4] = {};

  const int c1 = wid * 64 + lane;
  const int c2 = c1 + 256;
  const __bf16* Ar1 = A + (mBlock + (c1 >> 2)) * Dd + (c1 & 3) * 8;
  const __bf16* Ar2 = A + (mBlock + (c2 >> 2)) * Dd + (c2 & 3) * 8;
  const __bf16* Wr1 = W + (nBlock + (c1 >> 2)) * Dd + (c1 & 3) * 8;
  const __bf16* Wr2 = W + (nBlock + (c2 >> 2)) * Dd + (c2 & 3) * 8;
  __bf16* ldsA1 = sA + (wid * 64) * 8;
  __bf16* ldsA2 = sA + (wid * 64 + 256) * 8;
  __bf16* ldsB1 = sB + (wid * 64) * 8;
  __bf16* ldsB2 = sB + (wid * 64 + 256) * 8;

  for (int k0 = 0; k0 < Dd; k0 += 32) {
    gl_lds16(Ar1 + k0, ldsA1);
    gl_lds16(Ar2 + k0, ldsA2);
    gl_lds16(Wr1 + k0, ldsB1);
    gl_lds16(Wr2 + k0, ldsB2);
    __syncthreads();

    bf16x8 aF[4], bF[4];
#pragma unroll
    for (int mi = 0; mi < 4; mi++)
      aF[mi] = *(const bf16x8*)(sA + (waveM + mi * 16 + l15) * 32 + quad * 8);
#pragma unroll
    for (int ni = 0; ni < 4; ni++)
      bF[ni] = *(const bf16x8*)(sB + (waveN + ni * 16 + l15) * 32 + quad * 8);
#pragma unroll
    for (int mi = 0; mi < 4; mi++)
#pragma unroll
      for (int ni = 0; ni < 4; ni++)
        acc[mi][ni] = __builtin_amdgcn_mfma_f32_16x16x32_bf16(
            aF[mi], bF[ni], acc[mi][ni], 0, 0, 0);
    __syncthreads();
  }

  // C/D layout: col = lane&15, row = quad*4 + r.
#pragma unroll
  for (int ni = 0; ni < 4; ni++) {
    const int ng = nBlock + waveN + ni * 16 + l15;
    const float bv = (float)bias[ng];
#pragma unroll
    for (int mi = 0; mi < 4; mi++) {
      const int mg0 = mBlock + waveM + mi * 16 + quad * 4;
      if (MODE == 0 && which == 2) {
        const int b = mg0 >> 11, s0 = mg0 & 2047;
        const int h = ng >> 6, hd = ng & 63;
        bf16x4 pk;
#pragma unroll
        for (int r = 0; r < 4; r++) pk[r] = (__bf16)(acc[mi][ni][r] + bv);
        *(bf16x4*)((__bf16*)Out + (((b * Hh + h) * HD + hd) * Ss) + s0) = pk;
      } else {
#pragma unroll
        for (int r = 0; r < 4; r++) {
          float v = acc[mi][ni][r] + bv;
          const int m = mg0 + r;
          if (MODE == 0) {
            if (which == 0) v *= SCL2;  // fold softmax scale+log2e into Q
            const int b = m >> 11, s = m & 2047;
            const int h = ng >> 6, hd = ng & 63;
            Out[(((b * Hh + h) * Ss + s) * HD) + hd] = (OutT)v;
          } else {
            Out[m * Dd + ng] = (OutT)v;
          }
        }
      }
    }
  }
}

// ---------------------------------------------------------------------------
// Flash attention r9: 32x32 MFMA, kv-split 2-way, no-max softmax,
// double-buffered async staging (raw s_barrier + manual vmcnt — the tile
// in flight is NEVER drained by a barrier), P via register shfl exchange.
// Per-buffer LDS layout: K[hdhalf][kv64][32] (8KB) | V[kvhalf][hd64][32] (8KB)
// r9: 16B slots within each 64B row are XOR-swizzled by ((row>>1)&3) —
// global_load_lds writes linearly, so the SOURCE address carries the
// permutation (rule: both-sides-or-neither), and every ds_read applies the
// same XOR. Spreads a wave's 64 b128 lanes over all 8 four-bank groups
// (was: 4 groups x 16 lanes = 16-way conflict, ~20% of CU-cycles).
// ---------------------------------------------------------------------------
__global__ __launch_bounds__(256, 4) void attn_fused(
    const __bf16* __restrict__ Qg, const __bf16* __restrict__ Kg,
    const __bf16* __restrict__ Vt, const float* __restrict__ Mf,
    __bf16* __restrict__ Og) {
  __shared__ __align__(16) union {
    __bf16 buf[2][8192];  // [buffer][K 4096 | V 4096]
    struct {
      float O[2][64][32];  // [qg][hd][q] kv-half-1 partial
      float L[2][32];
    } m;
  } sh;

  const int tid = threadIdx.x;
  const int lane = tid & 63;
  const int wid = tid >> 6;
  const int qg = wid & 1;
  const int kvh = wid >> 1;
  const int l31 = lane & 31;
  const int hi = lane >> 5;
  const int bh = blockIdx.y;
  const int b = bh >> 4;
  const int h = bh & 15;
  const int qw = blockIdx.x * 64 + qg * 32 + l31;  // this lane's q row

  const __bf16* Qp = Qg + (size_t)bh * Ss * HD;
  const __bf16* Kp = Kg + (size_t)bh * Ss * HD;
  const __bf16* Vp = Vt + (size_t)bh * HD * Ss;  // [hd][S]
  const float* Mrow = Mf + ((size_t)b * Ss + qw) * Ss + 32 * kvh + 4 * hi;

  // Q B-fragments in registers (B[k=hd][n=q]; lane: hd = 16k + 8hi + j).
  bf16x8 qf[4];
#pragma unroll
  for (int k = 0; k < 4; k++)
    qf[k] = *(const bf16x8*)(Qp + (size_t)qw * HD + k * 16 + hi * 8);

  const int cA = tid, cB = 256 + tid;
  // r9: row index (kv for K, hd for V) is (c&255)>>2 for both tiles, so one
  // swizzled slot serves both. Same 64B footprint per 4-lane group => global
  // coalescing unchanged.
#define STAGE_KV(BI, KVS)                                                     \
  {                                                                           \
    const int rwA = (cA & 255) >> 2, rwB = (cB & 255) >> 2;                   \
    const int slA = (cA & 3) ^ ((rwA >> 1) & 3);                              \
    const int slB = (cB & 3) ^ ((rwB >> 1) & 3);                              \
    __bf16* kb = sh.buf[BI];                                                  \
    gl_lds16(Kp + ((KVS) + rwA) * HD + (cA >> 8) * 32 + slA * 8, kb + cA * 8);\
    gl_lds16(Kp + ((KVS) + rwB) * HD + (cB >> 8) * 32 + slB * 8, kb + cB * 8);\
    __bf16* vb = sh.buf[BI] + 4096;                                           \
    gl_lds16(Vp + (size_t)rwA * Ss + (KVS) + (cA >> 8) * 32 + slA * 8,        \
             vb + cA * 8);                                                    \
    gl_lds16(Vp + (size_t)rwB * Ss + (KVS) + (cB >> 8) * 32 + slB * 8,        \
             vb + cB * 8);                                                    \
  }

  f32x16 o[2] = {};  // O^T partials: row=hd (C-layout), col=q
  f32x4 lacc = {0.f, 0.f, 0.f, 0.f};

  const int rsw = (l31 >> 1) & 3;  // r9: read-side slot XOR (row>>1)&3

  STAGE_KV(0, 0);  // prologue: tile 0 in flight (4 vm ops)

  for (int it = 0; it < 32; ++it) {
    const int kv0 = it * 64;
    const int bufc = it & 1;
    cfence();
    __builtin_amdgcn_s_barrier();  // A: all waves done reading buf[bufc^1]
    cfence();
    // Mask loads for CURRENT tile — issued before next-tile staging so the
    // compiler's auto-wait for them leaves the staged tile in flight.
    f32x4 mc[4];
#pragma unroll
    for (int g = 0; g < 4; g++) mc[g] = *(const f32x4*)(Mrow + kv0 + g * 8);
    cfence();  // pin issue order: mask(i) before stage(i+1)
    if (it < 31) {
      STAGE_KV(bufc ^ 1, kv0 + 64);  // +4 vm ops, stay in flight past barrier
      cfence();
      asm volatile("s_waitcnt vmcnt(8)" ::: "memory");  // drain tile i only
    } else {
      asm volatile("s_waitcnt vmcnt(4)" ::: "memory");  // drain tile 31
    }
    __builtin_amdgcn_s_barrier();  // B: everyone's tile-i data visible
    cfence();

    // S^T = K Q^T over this wave's kv half (A rows kv = 32*kvh + l31).
    f32x16 sacc = {};
#pragma unroll
    for (int k = 0; k < 4; k++) {
      const int ps = (((k & 1) << 1) | hi) ^ rsw;  // r9 swizzled slot
      bf16x8 kf = *(const bf16x8*)(sh.buf[bufc] +
                                   ((k >> 1) * 64 + kvh * 32 + l31) * 32 +
                                   ps * 8);
      sacc = __builtin_amdgcn_mfma_f32_32x32x16_bf16(kf, qf[k], sacc, 0, 0, 0);
    }

    // p = exp2(s + m*log2e); C-layout: reg g*4+r <-> kv = 32kvh+g*8+4hi+r.
    f32x4 sv[4];
#pragma unroll
    for (int g = 0; g < 4; g++)
#pragma unroll
      for (int r = 0; r < 4; r++)
        sv[g][r] = __builtin_amdgcn_exp2f(sacc[g * 4 + r] + mc[g][r] * LOG2E);
    lacc += (sv[0] + sv[1]) + (sv[2] + sv[3]);

    // P^T B-fragments via register exchange (no LDS round-trip):
    // B-frag needs kv = ks*16 + 8hi + e; lane holds kv = 8g + 4hi + r.
    // hi=0 sends g1,g3 / receives partner g0,g2; hi=1 symmetric.
    bf16x4 pk[4];
#pragma unroll
    for (int g = 0; g < 4; g++)
#pragma unroll
      for (int r = 0; r < 4; r++) pk[g][r] = (__bf16)sv[g][r];
    union pu { bf16x4 v; uint32_t w[2]; };
    pu s0, s1, r0, r1;
    s0.v = hi ? pk[0] : pk[1];
    s1.v = hi ? pk[2] : pk[3];
    r0.w[0] = __shfl_xor((int)s0.w[0], 32);
    r0.w[1] = __shfl_xor((int)s0.w[1], 32);
    r1.w[0] = __shfl_xor((int)s1.w[0], 32);
    r1.w[1] = __shfl_xor((int)s1.w[1], 32);
    bf16x8 pf[2];
    {
      bf16x4 lo0 = hi ? r0.v : pk[0], hi0 = hi ? pk[1] : r0.v;
      bf16x4 lo1 = hi ? r1.v : pk[2], hi1 = hi ? pk[3] : r1.v;
#pragma unroll
      for (int e = 0; e < 4; e++) {
        pf[0][e] = lo0[e]; pf[0][e + 4] = hi0[e];
        pf[1][e] = lo1[e]; pf[1][e + 4] = hi1[e];
      }
    }

    // O^T += V^T P^T (contraction over wave's kv 32: 2 ksteps).
#pragma unroll
    for (int k = 0; k < 2; k++)
#pragma unroll
      for (int hb = 0; hb < 2; hb++) {
        const int ps = ((k << 1) | hi) ^ rsw;  // r9 swizzled slot
        bf16x8 vf = *(const bf16x8*)(sh.buf[bufc] + 4096 +
                                     (kvh * 64 + hb * 32 + l31) * 32 +
                                     ps * 8);
        o[hb] = __builtin_amdgcn_mfma_f32_32x32x16_bf16(vf, pf[k], o[hb],
                                                        0, 0, 0);
      }
  }

  float l = lacc[0] + lacc[1] + lacc[2] + lacc[3];
  l += __shfl_xor(l, 32);

  __syncthreads();  // all compute done; union switches to merge arrays
  // Merge kv-halves (plain add — no-max softmax has no rescale factor).
  if (kvh == 1) {
#pragma unroll
    for (int hb = 0; hb < 2; hb++)
#pragma unroll
      for (int r = 0; r < 16; r++) {
        const int hd = hb * 32 + (r & 3) + 8 * (r >> 2) + 4 * hi;
        sh.m.O[qg][hd][l31] = o[hb][r];
      }
    if (hi == 0) sh.m.L[qg][l31] = l;
  }
  __syncthreads();
  if (kvh == 0) {
#pragma unroll
    for (int hb = 0; hb < 2; hb++)
#pragma unroll
      for (int r = 0; r < 16; r++) {
        const int hd = hb * 32 + (r & 3) + 8 * (r >> 2) + 4 * hi;
        o[hb][r] += sh.m.O[qg][hd][l31];
      }
    l += sh.m.L[qg][l31];
    const float inv = 1.0f / l;
    __bf16* Ow = Og + (((size_t)b * Ss + qw) * Hh + h) * HD;
#pragma unroll
    for (int hb = 0; hb < 2; hb++)
#pragma unroll
      for (int g = 0; g < 4; g++) {
        const int hd = hb * 32 + g * 8 + 4 * hi;
        bf16x2 w0, w1;
        w0[0] = (__bf16)(o[hb][g * 4 + 0] * inv);
        w0[1] = (__bf16)(o[hb][g * 4 + 1] * inv);
        w1[0] = (__bf16)(o[hb][g * 4 + 2] * inv);
        w1[1] = (__bf16)(o[hb][g * 4 + 3] * inv);
        *(bf16x2*)(Ow + hd) = w0;
        *(bf16x2*)(Ow + hd + 2) = w1;
      }
  }
}

// ---------------------------------------------------------------------------
extern "C" void kernel_launch(void* const* d_in, const int* in_sizes, int n_in,
                              void* d_out, int out_size, void* d_ws,
                              size_t ws_size, hipStream_t stream) {
  if (ws_size < WS_NEED) return;

  __bf16* ws = (__bf16*)d_ws;
  const __bf16* hsC = ws + CAN_HS;
  const __bf16* WqC = ws + CAN_WQ;
  const __bf16* bqC = ws + CAN_BQ;
  const __bf16* WkC = ws + CAN_WK;
  const __bf16* bkC = ws + CAN_BK;
  const __bf16* WvC = ws + CAN_WV;
  const __bf16* bvC = ws + CAN_BV;
  const __bf16* WoC = ws + CAN_WO;
  const __bf16* boC = ws + CAN_BO;
  __bf16* Q = ws + CAN_END;
  __bf16* K = Q + TSZ;
  __bf16* V = K + TSZ;  // transposed layout [B,H,HD,S]
  __bf16* AW = V + TSZ;
  float* out = (float*)d_out;

  canon_kernel<<<2048, 256, 0, stream>>>(
      (const float*)d_in[0], (const float*)d_in[2], (const float*)d_in[3],
      (const float*)d_in[4], (const float*)d_in[5], (const float*)d_in[6],
      (const float*)d_in[7], (const float*)d_in[8], (const float*)d_in[9], ws);
  gemm_bt<0, __bf16><<<dim3(32, 24), 256, 0, stream>>>(
      hsC, WqC, WkC, WvC, bqC, bkC, bvC, Q, K, V);
  attn_fused<<<dim3(32, 32), 256, 0, stream>>>(Q, K, V, (const float*)d_in[1],
                                               AW);
  gemm_bt<1, float><<<dim3(32, 8), 256, 0, stream>>>(
      AW, WoC, WoC, WoC, boC, boC, boC, out, out, out);
}

// Round 3
// 257.162 us; speedup vs baseline: 1.0013x; 1.0006x over previous
//
#include <hip/hip_runtime.h>
#include <hip/hip_bf16.h>
#include <stdint.h>

// B=2, S=2048, D=1024, H=16, HD=64. Inputs fp32, d_out fp32 (resolved r1-r3).
// canon fp32->bf16 -> QKV GEMM (Q pre-scaled by 0.125*log2e; V transposed
// [B,H,HD,S]) -> flash attn (32x32 MFMA, kv-split 2-way, no-max exp2 softmax)
// -> out-proj GEMM fp32.
// r9: XOR-swizzled K/V LDS (conflicts 12.6M->4.19M, residual = shfl ds ops).
// r10 (FAILED): v_permlane32_swap operand order corrupted P halves.
// r11: revert P-exchange to proven __shfl_xor; KEEP the r10 schedule —
// ONE barrier/iter, mask prefetch 1 iter ahead + folded into MFMA C-init,
// setprio around MFMA clusters, LDS padded for even 4-blocks/CU packing.
#define Bb 2
#define Ss 2048
#define Dd 1024
#define Hh 16
#define HD 64

typedef __attribute__((ext_vector_type(8))) __bf16 bf16x8;
typedef __attribute__((ext_vector_type(4))) __bf16 bf16x4;
typedef __attribute__((ext_vector_type(2))) __bf16 bf16x2;
typedef __attribute__((ext_vector_type(4))) float f32x4;
typedef __attribute__((ext_vector_type(16))) float f32x16;

#define LOG2E 1.44269504088896f
#define SCL2 (0.125f * LOG2E)

// ---- workspace layout (bf16 elements) --------------------------------------
#define HS_N   (Bb * Ss * Dd)
#define W_N    (Dd * Dd)
#define B_N    (Dd)
#define CAN_HS 0
#define CAN_WQ (CAN_HS + HS_N)
#define CAN_BQ (CAN_WQ + W_N)
#define CAN_WK (CAN_BQ + B_N)
#define CAN_BK (CAN_WK + W_N)
#define CAN_WV (CAN_BK + B_N)
#define CAN_BV (CAN_WV + W_N)
#define CAN_WO (CAN_BV + B_N)
#define CAN_BO (CAN_WO + W_N)
#define CAN_END (CAN_BO + B_N)
#define TSZ    (Bb * Hh * Ss * HD)
#define WS_ELEMS (CAN_END + 4 * TSZ)
#define WS_NEED ((size_t)WS_ELEMS * 2)

__device__ __forceinline__ void gl_lds16(const __bf16* g, __bf16* l) {
  __builtin_amdgcn_global_load_lds(
      (const __attribute__((address_space(1))) void*)g,
      (__attribute__((address_space(3))) void*)l,
      16, 0, 0);
}

__device__ __forceinline__ void cfence() { asm volatile("" ::: "memory"); }

// fp32 -> bf16 canonicalization (segment table; r4 postmortem).
__global__ void canon_kernel(const float* hs, const float* Wq, const float* bq,
                             const float* Wk, const float* bk, const float* Wv,
                             const float* bv, const float* Wo, const float* bo,
                             __bf16* __restrict__ dst) {
  const float* srcs[9] = {hs, Wq, bq, Wk, bk, Wv, bv, Wo, bo};
  const long starts[10] = {CAN_HS, CAN_WQ, CAN_BQ, CAN_WK, CAN_BK,
                           CAN_WV, CAN_BV, CAN_WO, CAN_BO, CAN_END};
  const long nchunks = CAN_END / 8;
  for (long c = blockIdx.x * blockDim.x + threadIdx.x; c < nchunks;
       c += (long)gridDim.x * blockDim.x) {
    const long i = c * 8;
    int seg = 0;
#pragma unroll
    for (int t = 1; t < 9; t++) seg += (i >= starts[t]) ? 1 : 0;
    const float* s = srcs[seg] + (i - starts[seg]);
    bf16x8 v;
#pragma unroll
    for (int e = 0; e < 8; e++) v[e] = (__bf16)s[e];
    *(bf16x8*)(dst + i) = v;
  }
}

// ---------------------------------------------------------------------------
// GEMM: C[4096, 1024(x3)] = A @ W^T + bias (bf16 in).
// r10: sA padded so LDS/block = 41472 B -> max 3 blocks/CU (768 = 256x3
// exactly balanced; guards against 4/idle uneven packing).
// ---------------------------------------------------------------------------
template <int MODE, typename OutT>
__global__ __launch_bounds__(256, 2) void gemm_bt(
    const __bf16* __restrict__ A,
    const __bf16* __restrict__ W0, const __bf16* __restrict__ W1,
    const __bf16* __restrict__ W2,
    const __bf16* __restrict__ b0, const __bf16* __restrict__ b1,
    const __bf16* __restrict__ b2,
    OutT* __restrict__ O0, OutT* __restrict__ O1, OutT* __restrict__ O2) {
  __shared__ __align__(16) __bf16 sA[128 * 32 + 12544];  // pad -> 3 blk/CU
  __shared__ __align__(16) __bf16 sB[128 * 32];
  const int tid = threadIdx.x;
  const int lane = tid & 63;
  const int wid = tid >> 6;
  const int quad = lane >> 4;
  const int l15 = lane & 15;
  const int mBlock = blockIdx.x * 128;

  const __bf16* W;
  const __bf16* bias;
  OutT* Out;
  int nBlock, which = 0;
  if (MODE == 0) {
    which = blockIdx.y >> 3;  // 0:Q 1:K 2:V
    nBlock = (blockIdx.y & 7) * 128;
    W = which == 0 ? W0 : (which == 1 ? W1 : W2);
    bias = which == 0 ? b0 : (which == 1 ? b1 : b2);
    Out = which == 0 ? O0 : (which == 1 ? O1 : O2);
  } else {
    nBlock = blockIdx.y * 128;
    W = W0;
    bias = b0;
    Out = O0;
  }

  const int waveM = (wid >> 1) * 64;
  const int waveN = (wid & 1) * 64;

  f32x4 acc[4][4] = {};

  const int c1 = wid * 64 + lane;
  const int c2 = c1 + 256;
  const __bf16* Ar1 = A + (mBlock + (c1 >> 2)) * Dd + (c1 & 3) * 8;
  const __bf16* Ar2 = A + (mBlock + (c2 >> 2)) * Dd + (c2 & 3) * 8;
  const __bf16* Wr1 = W + (nBlock + (c1 >> 2)) * Dd + (c1 & 3) * 8;
  const __bf16* Wr2 = W + (nBlock + (c2 >> 2)) * Dd + (c2 & 3) * 8;
  __bf16* ldsA1 = sA + (wid * 64) * 8;
  __bf16* ldsA2 = sA + (wid * 64 + 256) * 8;
  __bf16* ldsB1 = sB + (wid * 64) * 8;
  __bf16* ldsB2 = sB + (wid * 64 + 256) * 8;

  for (int k0 = 0; k0 < Dd; k0 += 32) {
    gl_lds16(Ar1 + k0, ldsA1);
    gl_lds16(Ar2 + k0, ldsA2);
    gl_lds16(Wr1 + k0, ldsB1);
    gl_lds16(Wr2 + k0, ldsB2);
    __syncthreads();

    bf16x8 aF[4], bF[4];
#pragma unroll
    for (int mi = 0; mi < 4; mi++)
      aF[mi] = *(const bf16x8*)(sA + (waveM + mi * 16 + l15) * 32 + quad * 8);
#pragma unroll
    for (int ni = 0; ni < 4; ni++)
      bF[ni] = *(const bf16x8*)(sB + (waveN + ni * 16 + l15) * 32 + quad * 8);
#pragma unroll
    for (int mi = 0; mi < 4; mi++)
#pragma unroll
      for (int ni = 0; ni < 4; ni++)
        acc[mi][ni] = __builtin_amdgcn_mfma_f32_16x16x32_bf16(
            aF[mi], bF[ni], acc[mi][ni], 0, 0, 0);
    __syncthreads();
  }

  // C/D layout: col = lane&15, row = quad*4 + r.
#pragma unroll
  for (int ni = 0; ni < 4; ni++) {
    const int ng = nBlock + waveN + ni * 16 + l15;
    const float bv = (float)bias[ng];
#pragma unroll
    for (int mi = 0; mi < 4; mi++) {
      const int mg0 = mBlock + waveM + mi * 16 + quad * 4;
      if (MODE == 0 && which == 2) {
        const int b = mg0 >> 11, s0 = mg0 & 2047;
        const int h = ng >> 6, hd = ng & 63;
        bf16x4 pk;
#pragma unroll
        for (int r = 0; r < 4; r++) pk[r] = (__bf16)(acc[mi][ni][r] + bv);
        *(bf16x4*)((__bf16*)Out + (((b * Hh + h) * HD + hd) * Ss) + s0) = pk;
      } else {
#pragma unroll
        for (int r = 0; r < 4; r++) {
          float v = acc[mi][ni][r] + bv;
          const int m = mg0 + r;
          if (MODE == 0) {
            if (which == 0) v *= SCL2;  // fold softmax scale+log2e into Q
            const int b = m >> 11, s = m & 2047;
            const int h = ng >> 6, hd = ng & 63;
            Out[(((b * Hh + h) * Ss + s) * HD) + hd] = (OutT)v;
          } else {
            Out[m * Dd + ng] = (OutT)v;
          }
        }
      }
    }
  }
}

// ---------------------------------------------------------------------------
// Flash attention r11: 32x32 MFMA, kv-split 2-way, no-max softmax.
// Schedule per iter: vmcnt(0) -> barrier -> stage(i+1)+mask(i+1) -> compute(i).
// ONE barrier per iteration. Safety: each wave's LDS reads of buf[(i-1)&1]
// completed (results in regs) before it reaches barrier(i), so stage(i+1)
// overwriting that buffer is safe; own vmcnt(0) before barrier(i) + barrier
// proves tile-i data and mask(i) regs are resident for everyone after it.
// Per-buffer LDS layout: K[hdhalf][kv64][32] (8KB) | V[kvhalf][hd64][32] (8KB)
// 16B slots XOR-swizzled by ((row>>1)&3) on BOTH source addr and read (r9).
// Buffer padded 2*9216 (36864 B) -> exactly 4 blocks/CU (even packing).
// P-exchange: __shfl_xor 32 register path (r9-proven).
// ---------------------------------------------------------------------------
__global__ __launch_bounds__(256, 4) void attn_fused(
    const __bf16* __restrict__ Qg, const __bf16* __restrict__ Kg,
    const __bf16* __restrict__ Vt, const float* __restrict__ Mf,
    __bf16* __restrict__ Og) {
  __shared__ __align__(16) union {
    __bf16 buf[2][9216];  // [buffer][K 4096 | V 4096 | pad 1024]
    struct {
      float O[2][64][32];  // [qg][hd][q] kv-half-1 partial
      float L[2][32];
    } m;
  } sh;

  const int tid = threadIdx.x;
  const int lane = tid & 63;
  const int wid = tid >> 6;
  const int qg = wid & 1;
  const int kvh = wid >> 1;
  const int l31 = lane & 31;
  const int hi = lane >> 5;
  const int bh = blockIdx.y;
  const int b = bh >> 4;
  const int h = bh & 15;
  const int qw = blockIdx.x * 64 + qg * 32 + l31;  // this lane's q row

  const __bf16* Qp = Qg + (size_t)bh * Ss * HD;
  const __bf16* Kp = Kg + (size_t)bh * Ss * HD;
  const __bf16* Vp = Vt + (size_t)bh * HD * Ss;  // [hd][S]
  const float* Mrow = Mf + ((size_t)b * Ss + qw) * Ss + 32 * kvh + 4 * hi;

  // Q B-fragments in registers (B[k=hd][n=q]; lane: hd = 16k + 8hi + j).
  bf16x8 qf[4];
#pragma unroll
  for (int k = 0; k < 4; k++)
    qf[k] = *(const bf16x8*)(Qp + (size_t)qw * HD + k * 16 + hi * 8);

  const int cA = tid, cB = 256 + tid;
  // Swizzled staging: row index is (c&255)>>2 for both tiles; slot XOR'd by
  // ((row>>1)&3). Same 64B footprint per 4-lane group => coalescing intact.
#define STAGE_KV(BI, KVS)                                                     \
  {                                                                           \
    const int rwA = (cA & 255) >> 2, rwB = (cB & 255) >> 2;                   \
    const int slA = (cA & 3) ^ ((rwA >> 1) & 3);                              \
    const int slB = (cB & 3) ^ ((rwB >> 1) & 3);                              \
    __bf16* kb = sh.buf[BI];                                                  \
    gl_lds16(Kp + ((KVS) + rwA) * HD + (cA >> 8) * 32 + slA * 8, kb + cA * 8);\
    gl_lds16(Kp + ((KVS) + rwB) * HD + (cB >> 8) * 32 + slB * 8, kb + cB * 8);\
    __bf16* vb = sh.buf[BI] + 4096;                                           \
    gl_lds16(Vp + (size_t)rwA * Ss + (KVS) + (cA >> 8) * 32 + slA * 8,        \
             vb + cA * 8);                                                    \
    gl_lds16(Vp + (size_t)rwB * Ss + (KVS) + (cB >> 8) * 32 + slB * 8,        \
             vb + cB * 8);                                                    \
  }

  f32x16 o[2] = {};  // O^T partials: row=hd (C-layout), col=q
  f32x4 lacc = {0.f, 0.f, 0.f, 0.f};

  const int rsw = (l31 >> 1) & 3;  // read-side slot XOR (row>>1)&3

  // Prologue: tile 0 staged + mask(0) prefetched (vm ops in flight).
  STAGE_KV(0, 0);
  f32x4 mcur[4], mnext[4];
#pragma unroll
  for (int g = 0; g < 4; g++) mcur[g] = *(const f32x4*)(Mrow + g * 8);

  for (int it = 0; it < 32; ++it) {
    const int bufc = it & 1;
    cfence();
    // Drain own stage(it) + mask regs (nothing for it+1 in flight yet).
    asm volatile("s_waitcnt vmcnt(0)" ::: "memory");
    cfence();
    __builtin_amdgcn_s_barrier();  // tile it visible; buf[bufc^1] free
    cfence();
    if (it < 31) {
      STAGE_KV(bufc ^ 1, (it + 1) * 64);  // overlaps whole compute phase
      cfence();
#pragma unroll
      for (int g = 0; g < 4; g++)
        mnext[g] = *(const f32x4*)(Mrow + (it + 1) * 64 + g * 8);
      cfence();
    }

    // S^T = K Q^T + mask*log2e (C-init carries the mask; layout identical:
    // reg g*4+r <-> kv = 8g+4hi+r, col q = l31).
    f32x16 sacc;
#pragma unroll
    for (int g = 0; g < 4; g++)
#pragma unroll
      for (int r = 0; r < 4; r++) sacc[g * 4 + r] = mcur[g][r] * LOG2E;
    __builtin_amdgcn_s_setprio(1);
#pragma unroll
    for (int k = 0; k < 4; k++) {
      const int ps = (((k & 1) << 1) | hi) ^ rsw;  // swizzled slot
      bf16x8 kf = *(const bf16x8*)(sh.buf[bufc] +
                                   ((k >> 1) * 64 + kvh * 32 + l31) * 32 +
                                   ps * 8);
      sacc = __builtin_amdgcn_mfma_f32_32x32x16_bf16(kf, qf[k], sacc, 0, 0, 0);
    }
    __builtin_amdgcn_s_setprio(0);

    // p = exp2(s); row-sum into lacc.
    f32x4 sv[4];
#pragma unroll
    for (int g = 0; g < 4; g++)
#pragma unroll
      for (int r = 0; r < 4; r++)
        sv[g][r] = __builtin_amdgcn_exp2f(sacc[g * 4 + r]);
    lacc += (sv[0] + sv[1]) + (sv[2] + sv[3]);

    // P^T B-fragments via register exchange (r9-proven):
    // B-frag needs kv = ks*16 + 8hi + e; lane holds kv = 8g + 4hi + r.
    // hi=0 sends g1,g3 / receives partner g0,g2; hi=1 symmetric.
    bf16x4 pk[4];
#pragma unroll
    for (int g = 0; g < 4; g++)
#pragma unroll
      for (int r = 0; r < 4; r++) pk[g][r] = (__bf16)sv[g][r];
    union pu { bf16x4 v; uint32_t w[2]; };
    pu s0, s1, r0, r1;
    s0.v = hi ? pk[0] : pk[1];
    s1.v = hi ? pk[2] : pk[3];
    r0.w[0] = __shfl_xor((int)s0.w[0], 32);
    r0.w[1] = __shfl_xor((int)s0.w[1], 32);
    r1.w[0] = __shfl_xor((int)s1.w[0], 32);
    r1.w[1] = __shfl_xor((int)s1.w[1], 32);
    bf16x8 pf[2];
    {
      bf16x4 lo0 = hi ? r0.v : pk[0], hi0 = hi ? pk[1] : r0.v;
      bf16x4 lo1 = hi ? r1.v : pk[2], hi1 = hi ? pk[3] : r1.v;
#pragma unroll
      for (int e = 0; e < 4; e++) {
        pf[0][e] = lo0[e]; pf[0][e + 4] = hi0[e];
        pf[1][e] = lo1[e]; pf[1][e + 4] = hi1[e];
      }
    }

    // O^T += V^T P^T (contraction over wave's kv 32: 2 ksteps).
    __builtin_amdgcn_s_setprio(1);
#pragma unroll
    for (int k = 0; k < 2; k++)
#pragma unroll
      for (int hb = 0; hb < 2; hb++) {
        const int ps = ((k << 1) | hi) ^ rsw;  // swizzled slot
        bf16x8 vf = *(const bf16x8*)(sh.buf[bufc] + 4096 +
                                     (kvh * 64 + hb * 32 + l31) * 32 +
                                     ps * 8);
        o[hb] = __builtin_amdgcn_mfma_f32_32x32x16_bf16(vf, pf[k], o[hb],
                                                        0, 0, 0);
      }
    __builtin_amdgcn_s_setprio(0);

#pragma unroll
    for (int g = 0; g < 4; g++) mcur[g] = mnext[g];
  }

  float l = lacc[0] + lacc[1] + lacc[2] + lacc[3];
  l += __shfl_xor(l, 32);

  __syncthreads();  // all compute done; union switches to merge arrays
  // Merge kv-halves (plain add — no-max softmax has no rescale factor).
  if (kvh == 1) {
#pragma unroll
    for (int hb = 0; hb < 2; hb++)
#pragma unroll
      for (int r = 0; r < 16; r++) {
        const int hd = hb * 32 + (r & 3) + 8 * (r >> 2) + 4 * hi;
        sh.m.O[qg][hd][l31] = o[hb][r];
      }
    if (hi == 0) sh.m.L[qg][l31] = l;
  }
  __syncthreads();
  if (kvh == 0) {
#pragma unroll
    for (int hb = 0; hb < 2; hb++)
#pragma unroll
      for (int r = 0; r < 16; r++) {
        const int hd = hb * 32 + (r & 3) + 8 * (r >> 2) + 4 * hi;
        o[hb][r] += sh.m.O[qg][hd][l31];
      }
    l += sh.m.L[qg][l31];
    const float inv = 1.0f / l;
    __bf16* Ow = Og + (((size_t)b * Ss + qw) * Hh + h) * HD;
#pragma unroll
    for (int hb = 0; hb < 2; hb++)
#pragma unroll
      for (int g = 0; g < 4; g++) {
        const int hd = hb * 32 + g * 8 + 4 * hi;
        bf16x2 w0, w1;
        w0[0] = (__bf16)(o[hb][g * 4 + 0] * inv);
        w0[1] = (__bf16)(o[hb][g * 4 + 1] * inv);
        w1[0] = (__bf16)(o[hb][g * 4 + 2] * inv);
        w1[1] = (__bf16)(o[hb][g * 4 + 3] * inv);
        *(bf16x2*)(Ow + hd) = w0;
        *(bf16x2*)(Ow + hd + 2) = w1;
      }
  }
}

// ---------------------------------------------------------------------------
extern "C" void kernel_launch(void* const* d_in, const int* in_sizes, int n_in,
                              void* d_out, int out_size, void* d_ws,
                              size_t ws_size, hipStream_t stream) {
  if (ws_size < WS_NEED) return;

  __bf16* ws = (__bf16*)d_ws;
  const __bf16* hsC = ws + CAN_HS;
  const __bf16* WqC = ws + CAN_WQ;
  const __bf16* bqC = ws + CAN_BQ;
  const __bf16* WkC = ws + CAN_WK;
  const __bf16* bkC = ws + CAN_BK;
  const __bf16* WvC = ws + CAN_WV;
  const __bf16* bvC = ws + CAN_BV;
  const __bf16* WoC = ws + CAN_WO;
  const __bf16* boC = ws + CAN_BO;
  __bf16* Q = ws + CAN_END;
  __bf16* K = Q + TSZ;
  __bf16* V = K + TSZ;  // transposed layout [B,H,HD,S]
  __bf16* AW = V + TSZ;
  float* out = (float*)d_out;

  canon_kernel<<<2048, 256, 0, stream>>>(
      (const float*)d_in[0], (const float*)d_in[2], (const float*)d_in[3],
      (const float*)d_in[4], (const float*)d_in[5], (const float*)d_in[6],
      (const float*)d_in[7], (const float*)d_in[8], (const float*)d_in[9], ws);
  gemm_bt<0, __bf16><<<dim3(32, 24), 256, 0, stream>>>(
      hsC, WqC, WkC, WvC, bqC, bkC, bvC, Q, K, V);
  attn_fused<<<dim3(32, 32), 256, 0, stream>>>(Q, K, V, (const float*)d_in[1],
                                               AW);
  gemm_bt<1, float><<<dim3(32, 8), 256, 0, stream>>>(
      AW, WoC, WoC, WoC, boC, boC, boC, out, out, out);
}

// Round 4
// 236.347 us; speedup vs baseline: 1.0894x; 1.0881x over previous
//
#include <hip/hip_runtime.h>
#include <hip/hip_bf16.h>
#include <stdint.h>

// B=2, S=2048, D=1024, H=16, HD=64. Inputs fp32, d_out fp32 (resolved r1-r3).
// canon fp32->bf16 -> QKV GEMM (Q pre-scaled by 0.125*log2e; V transposed
// [B,H,HD,S]) -> flash attn (32x32 MFMA, kv-split 2-way, no-max exp2 softmax)
// -> out-proj GEMM fp32.
// r9: XOR-swizzled K/V LDS (conflicts 12.6M->4.19M, residual = shfl ds ops).
// r11: one-barrier schedule + mask C-init fold — NEUTRAL (stall is elsewhere).
// r12: the 64-line MASK GATHER was the stall (4096 line-req/CU/iter ~= the
// unexplained 4100 cyc/iter). Mask tile now staged via global_load_lds
// (coalesced 16B chunks), single-buffered in LDS with read->barrier->stage
// discipline; read side ds_read_b128 with source-carried XOR swizzle
// (phys16 = l16 ^ (q&7), involution — rule #21). LDS 48KB -> 3 blocks/CU.
#define Bb 2
#define Ss 2048
#define Dd 1024
#define Hh 16
#define HD 64

typedef __attribute__((ext_vector_type(8))) __bf16 bf16x8;
typedef __attribute__((ext_vector_type(4))) __bf16 bf16x4;
typedef __attribute__((ext_vector_type(2))) __bf16 bf16x2;
typedef __attribute__((ext_vector_type(4))) float f32x4;
typedef __attribute__((ext_vector_type(16))) float f32x16;

#define LOG2E 1.44269504088896f
#define SCL2 (0.125f * LOG2E)

// ---- workspace layout (bf16 elements) --------------------------------------
#define HS_N   (Bb * Ss * Dd)
#define W_N    (Dd * Dd)
#define B_N    (Dd)
#define CAN_HS 0
#define CAN_WQ (CAN_HS + HS_N)
#define CAN_BQ (CAN_WQ + W_N)
#define CAN_WK (CAN_BQ + B_N)
#define CAN_BK (CAN_WK + W_N)
#define CAN_WV (CAN_BK + B_N)
#define CAN_BV (CAN_WV + W_N)
#define CAN_WO (CAN_BV + B_N)
#define CAN_BO (CAN_WO + W_N)
#define CAN_END (CAN_BO + B_N)
#define TSZ    (Bb * Hh * Ss * HD)
#define WS_ELEMS (CAN_END + 4 * TSZ)
#define WS_NEED ((size_t)WS_ELEMS * 2)

__device__ __forceinline__ void gl_lds16(const __bf16* g, __bf16* l) {
  __builtin_amdgcn_global_load_lds(
      (const __attribute__((address_space(1))) void*)g,
      (__attribute__((address_space(3))) void*)l,
      16, 0, 0);
}

__device__ __forceinline__ void gl_lds16f(const float* g, float* l) {
  __builtin_amdgcn_global_load_lds(
      (const __attribute__((address_space(1))) void*)g,
      (__attribute__((address_space(3))) void*)l,
      16, 0, 0);
}

__device__ __forceinline__ void cfence() { asm volatile("" ::: "memory"); }

// fp32 -> bf16 canonicalization (segment table; r4 postmortem).
__global__ void canon_kernel(const float* hs, const float* Wq, const float* bq,
                             const float* Wk, const float* bk, const float* Wv,
                             const float* bv, const float* Wo, const float* bo,
                             __bf16* __restrict__ dst) {
  const float* srcs[9] = {hs, Wq, bq, Wk, bk, Wv, bv, Wo, bo};
  const long starts[10] = {CAN_HS, CAN_WQ, CAN_BQ, CAN_WK, CAN_BK,
                           CAN_WV, CAN_BV, CAN_WO, CAN_BO, CAN_END};
  const long nchunks = CAN_END / 8;
  for (long c = blockIdx.x * blockDim.x + threadIdx.x; c < nchunks;
       c += (long)gridDim.x * blockDim.x) {
    const long i = c * 8;
    int seg = 0;
#pragma unroll
    for (int t = 1; t < 9; t++) seg += (i >= starts[t]) ? 1 : 0;
    const float* s = srcs[seg] + (i - starts[seg]);
    bf16x8 v;
#pragma unroll
    for (int e = 0; e < 8; e++) v[e] = (__bf16)s[e];
    *(bf16x8*)(dst + i) = v;
  }
}

// ---------------------------------------------------------------------------
// GEMM: C[4096, 1024(x3)] = A @ W^T + bias (bf16 in).  (unchanged from r11)
// ---------------------------------------------------------------------------
template <int MODE, typename OutT>
__global__ __launch_bounds__(256, 2) void gemm_bt(
    const __bf16* __restrict__ A,
    const __bf16* __restrict__ W0, const __bf16* __restrict__ W1,
    const __bf16* __restrict__ W2,
    const __bf16* __restrict__ b0, const __bf16* __restrict__ b1,
    const __bf16* __restrict__ b2,
    OutT* __restrict__ O0, OutT* __restrict__ O1, OutT* __restrict__ O2) {
  __shared__ __align__(16) __bf16 sA[128 * 32 + 12544];  // pad -> 3 blk/CU
  __shared__ __align__(16) __bf16 sB[128 * 32];
  const int tid = threadIdx.x;
  const int lane = tid & 63;
  const int wid = tid >> 6;
  const int quad = lane >> 4;
  const int l15 = lane & 15;
  const int mBlock = blockIdx.x * 128;

  const __bf16* W;
  const __bf16* bias;
  OutT* Out;
  int nBlock, which = 0;
  if (MODE == 0) {
    which = blockIdx.y >> 3;  // 0:Q 1:K 2:V
    nBlock = (blockIdx.y & 7) * 128;
    W = which == 0 ? W0 : (which == 1 ? W1 : W2);
    bias = which == 0 ? b0 : (which == 1 ? b1 : b2);
    Out = which == 0 ? O0 : (which == 1 ? O1 : O2);
  } else {
    nBlock = blockIdx.y * 128;
    W = W0;
    bias = b0;
    Out = O0;
  }

  const int waveM = (wid >> 1) * 64;
  const int waveN = (wid & 1) * 64;

  f32x4 acc[4][4] = {};

  const int c1 = wid * 64 + lane;
  const int c2 = c1 + 256;
  const __bf16* Ar1 = A + (mBlock + (c1 >> 2)) * Dd + (c1 & 3) * 8;
  const __bf16* Ar2 = A + (mBlock + (c2 >> 2)) * Dd + (c2 & 3) * 8;
  const __bf16* Wr1 = W + (nBlock + (c1 >> 2)) * Dd + (c1 & 3) * 8;
  const __bf16* Wr2 = W + (nBlock + (c2 >> 2)) * Dd + (c2 & 3) * 8;
  __bf16* ldsA1 = sA + (wid * 64) * 8;
  __bf16* ldsA2 = sA + (wid * 64 + 256) * 8;
  __bf16* ldsB1 = sB + (wid * 64) * 8;
  __bf16* ldsB2 = sB + (wid * 64 + 256) * 8;

  for (int k0 = 0; k0 < Dd; k0 += 32) {
    gl_lds16(Ar1 + k0, ldsA1);
    gl_lds16(Ar2 + k0, ldsA2);
    gl_lds16(Wr1 + k0, ldsB1);
    gl_lds16(Wr2 + k0, ldsB2);
    __syncthreads();

    bf16x8 aF[4], bF[4];
#pragma unroll
    for (int mi = 0; mi < 4; mi++)
      aF[mi] = *(const bf16x8*)(sA + (waveM + mi * 16 + l15) * 32 + quad * 8);
#pragma unroll
    for (int ni = 0; ni < 4; ni++)
      bF[ni] = *(const bf16x8*)(sB + (waveN + ni * 16 + l15) * 32 + quad * 8);
#pragma unroll
    for (int mi = 0; mi < 4; mi++)
#pragma unroll
      for (int ni = 0; ni < 4; ni++)
        acc[mi][ni] = __builtin_amdgcn_mfma_f32_16x16x32_bf16(
            aF[mi], bF[ni], acc[mi][ni], 0, 0, 0);
    __syncthreads();
  }

  // C/D layout: col = lane&15, row = quad*4 + r.
#pragma unroll
  for (int ni = 0; ni < 4; ni++) {
    const int ng = nBlock + waveN + ni * 16 + l15;
    const float bv = (float)bias[ng];
#pragma unroll
    for (int mi = 0; mi < 4; mi++) {
      const int mg0 = mBlock + waveM + mi * 16 + quad * 4;
      if (MODE == 0 && which == 2) {
        const int b = mg0 >> 11, s0 = mg0 & 2047;
        const int h = ng >> 6, hd = ng & 63;
        bf16x4 pk;
#pragma unroll
        for (int r = 0; r < 4; r++) pk[r] = (__bf16)(acc[mi][ni][r] + bv);
        *(bf16x4*)((__bf16*)Out + (((b * Hh + h) * HD + hd) * Ss) + s0) = pk;
      } else {
#pragma unroll
        for (int r = 0; r < 4; r++) {
          float v = acc[mi][ni][r] + bv;
          const int m = mg0 + r;
          if (MODE == 0) {
            if (which == 0) v *= SCL2;  // fold softmax scale+log2e into Q
            const int b = m >> 11, s = m & 2047;
            const int h = ng >> 6, hd = ng & 63;
            Out[(((b * Hh + h) * Ss + s) * HD) + hd] = (OutT)v;
          } else {
            Out[m * Dd + ng] = (OutT)v;
          }
        }
      }
    }
  }
}

// ---------------------------------------------------------------------------
// Flash attention r12: 32x32 MFMA, kv-split 2-way, no-max softmax.
// Mask tile staged via global_load_lds (coalesced) — kills the 64-line/instr
// per-lane mask gather that was ~4100 cyc/iter of TA pressure.
// Per iter: vmcnt(0) -> barrier A (tile i K/V+mask visible)
//   -> issue K/V stage(i+1) -> read mask(i) from LDS (ds_read_b128 x4)
//   -> lgkmcnt(0) -> barrier B (all mask reads done)
//   -> issue mask stage(i+1) (overwrite now safe) -> compute(i).
// LDS: kv[2][8KB K | 8KB V] double-buffered (source-swizzled, r9) +
// mk[64q][64kv] f32 single-buffered (source-swizzled phys16 = l16 ^ (q&7)).
// 49152 B -> 3 blocks/CU.
// ---------------------------------------------------------------------------
__global__ __launch_bounds__(256, 3) void attn_fused(
    const __bf16* __restrict__ Qg, const __bf16* __restrict__ Kg,
    const __bf16* __restrict__ Vt, const float* __restrict__ Mf,
    __bf16* __restrict__ Og) {
  __shared__ __align__(16) union {
    struct {
      __bf16 kv[2][8192];  // [buffer][K 4096 | V 4096]
      float mk[64 * 64];   // mask tile, 16 phys 16B-slots per q-row
    } s;
    struct {
      float O[2][64][32];  // [qg][hd][q] kv-half-1 partial
      float L[2][32];
    } m;
  } sh;

  const int tid = threadIdx.x;
  const int lane = tid & 63;
  const int wid = tid >> 6;
  const int qg = wid & 1;
  const int kvh = wid >> 1;
  const int l31 = lane & 31;
  const int hi = lane >> 5;
  const int bh = blockIdx.y;
  const int b = bh >> 4;
  const int h = bh & 15;
  const int qb0 = blockIdx.x * 64;          // block's first q row
  const int qw = qb0 + qg * 32 + l31;       // this lane's q row

  const __bf16* Qp = Qg + (size_t)bh * Ss * HD;
  const __bf16* Kp = Kg + (size_t)bh * Ss * HD;
  const __bf16* Vp = Vt + (size_t)bh * HD * Ss;  // [hd][S]
  const float* Mp = Mf + (size_t)b * Ss * Ss;

  // Q B-fragments in registers (B[k=hd][n=q]; lane: hd = 16k + 8hi + j).
  bf16x8 qf[4];
#pragma unroll
  for (int k = 0; k < 4; k++)
    qf[k] = *(const bf16x8*)(Qp + (size_t)qw * HD + k * 16 + hi * 8);

  const int cA = tid, cB = 256 + tid;
  // K/V staging (r9-proven): linear LDS dest (base + lane*16B as the DMA
  // requires), source carries the slot swizzle ((row>>1)&3).
#define STAGE_KV(BI, KVS)                                                     \
  {                                                                           \
    const int rwA = (cA & 255) >> 2, rwB = (cB & 255) >> 2;                   \
    const int slA = (cA & 3) ^ ((rwA >> 1) & 3);                              \
    const int slB = (cB & 3) ^ ((rwB >> 1) & 3);                              \
    __bf16* kb = sh.s.kv[BI];                                                 \
    gl_lds16(Kp + ((KVS) + rwA) * HD + (cA >> 8) * 32 + slA * 8, kb + cA * 8);\
    gl_lds16(Kp + ((KVS) + rwB) * HD + (cB >> 8) * 32 + slB * 8, kb + cB * 8);\
    __bf16* vb = sh.s.kv[BI] + 4096;                                          \
    gl_lds16(Vp + (size_t)rwA * Ss + (KVS) + (cA >> 8) * 32 + slA * 8,        \
             vb + cA * 8);                                                    \
    gl_lds16(Vp + (size_t)rwB * Ss + (KVS) + (cB >> 8) * 32 + slB * 8,        \
             vb + cB * 8);                                                    \
  }

  // Mask staging: 1024 16B-chunks; chunk c lands LINEARLY at LDS 16B-slot c
  // (row q = c>>4, phys16 = c&15). Read expects logical slot l16 at phys
  // l16 ^ (q&7) (involution), so the SOURCE fetches logical chunk
  // (c&15) ^ (q&7). Coalescing: same 4 lines per 16-lane group, permuted.
#define STAGE_M(KVS)                                                          \
  {                                                                           \
    _Pragma("unroll")                                                         \
    for (int rr = 0; rr < 4; rr++) {                                          \
      const int c = tid + rr * 256;                                           \
      const int mq = c >> 4;                                                  \
      const int kvi = ((c & 15) ^ (mq & 7)) * 4;                              \
      gl_lds16f(Mp + (size_t)(qb0 + mq) * Ss + (KVS) + kvi,                   \
                sh.s.mk + c * 4);                                             \
    }                                                                         \
  }

  f32x16 o[2] = {};  // O^T partials: row=hd (C-layout), col=q
  f32x4 lacc = {0.f, 0.f, 0.f, 0.f};

  const int rsw = (l31 >> 1) & 3;  // K/V read-side slot XOR (row>>1)&3

  // Prologue: tile 0 K/V + mask(0) staged.
  STAGE_KV(0, 0);
  STAGE_M(0);

  for (int it = 0; it < 32; ++it) {
    const int bufc = it & 1;
    cfence();
    asm volatile("s_waitcnt vmcnt(0)" ::: "memory");  // drain stage(it)
    cfence();
    __builtin_amdgcn_s_barrier();  // A: tile-i K/V + mask visible
    cfence();
    if (it < 31) {
      STAGE_KV(bufc ^ 1, (it + 1) * 64);  // K/V prefetch overlaps everything
      cfence();
    }

    // Read mask(i) tile from LDS: lane (l31,hi) wants rows q=qg*32+l31,
    // kv = 32kvh + 8g + 4hi + r  ->  logical slot l16 = 8kvh+2g+hi,
    // phys16 = l16 ^ (l31&7).
    f32x4 mc[4];
    const int mq = qg * 32 + l31;
#pragma unroll
    for (int g = 0; g < 4; g++) {
      const int p16 = (8 * kvh + 2 * g + hi) ^ (l31 & 7);
      mc[g] = *(const f32x4*)(sh.s.mk + mq * 64 + p16 * 4);
    }
    cfence();
    asm volatile("s_waitcnt lgkmcnt(0)" ::: "memory");  // mask reads done
    cfence();
    __builtin_amdgcn_s_barrier();  // B: all waves consumed mask(i)
    cfence();
    if (it < 31) {
      STAGE_M((it + 1) * 64);  // safe to overwrite mask tile now
      cfence();
    }

    // S^T = K Q^T + mask*log2e (C-init carries the mask; layout identical:
    // reg g*4+r <-> kv = 8g+4hi+r, col q = l31).
    f32x16 sacc;
#pragma unroll
    for (int g = 0; g < 4; g++)
#pragma unroll
      for (int r = 0; r < 4; r++) sacc[g * 4 + r] = mc[g][r] * LOG2E;
    __builtin_amdgcn_s_setprio(1);
#pragma unroll
    for (int k = 0; k < 4; k++) {
      const int ps = (((k & 1) << 1) | hi) ^ rsw;  // swizzled slot
      bf16x8 kf = *(const bf16x8*)(sh.s.kv[bufc] +
                                   ((k >> 1) * 64 + kvh * 32 + l31) * 32 +
                                   ps * 8);
      sacc = __builtin_amdgcn_mfma_f32_32x32x16_bf16(kf, qf[k], sacc, 0, 0, 0);
    }
    __builtin_amdgcn_s_setprio(0);

    // p = exp2(s); row-sum into lacc.
    f32x4 sv[4];
#pragma unroll
    for (int g = 0; g < 4; g++)
#pragma unroll
      for (int r = 0; r < 4; r++)
        sv[g][r] = __builtin_amdgcn_exp2f(sacc[g * 4 + r]);
    lacc += (sv[0] + sv[1]) + (sv[2] + sv[3]);

    // P^T B-fragments via register exchange (r9-proven):
    // B-frag needs kv = ks*16 + 8hi + e; lane holds kv = 8g + 4hi + r.
    // hi=0 sends g1,g3 / receives partner g0,g2; hi=1 symmetric.
    bf16x4 pk[4];
#pragma unroll
    for (int g = 0; g < 4; g++)
#pragma unroll
      for (int r = 0; r < 4; r++) pk[g][r] = (__bf16)sv[g][r];
    union pu { bf16x4 v; uint32_t w[2]; };
    pu s0, s1, r0, r1;
    s0.v = hi ? pk[0] : pk[1];
    s1.v = hi ? pk[2] : pk[3];
    r0.w[0] = __shfl_xor((int)s0.w[0], 32);
    r0.w[1] = __shfl_xor((int)s0.w[1], 32);
    r1.w[0] = __shfl_xor((int)s1.w[0], 32);
    r1.w[1] = __shfl_xor((int)s1.w[1], 32);
    bf16x8 pf[2];
    {
      bf16x4 lo0 = hi ? r0.v : pk[0], hi0 = hi ? pk[1] : r0.v;
      bf16x4 lo1 = hi ? r1.v : pk[2], hi1 = hi ? pk[3] : r1.v;
#pragma unroll
      for (int e = 0; e < 4; e++) {
        pf[0][e] = lo0[e]; pf[0][e + 4] = hi0[e];
        pf[1][e] = lo1[e]; pf[1][e + 4] = hi1[e];
      }
    }

    // O^T += V^T P^T (contraction over wave's kv 32: 2 ksteps).
    __builtin_amdgcn_s_setprio(1);
#pragma unroll
    for (int k = 0; k < 2; k++)
#pragma unroll
      for (int hb = 0; hb < 2; hb++) {
        const int ps = ((k << 1) | hi) ^ rsw;  // swizzled slot
        bf16x8 vf = *(const bf16x8*)(sh.s.kv[bufc] + 4096 +
                                     (kvh * 64 + hb * 32 + l31) * 32 +
                                     ps * 8);
        o[hb] = __builtin_amdgcn_mfma_f32_32x32x16_bf16(vf, pf[k], o[hb],
                                                        0, 0, 0);
      }
    __builtin_amdgcn_s_setprio(0);
  }

  float l = lacc[0] + lacc[1] + lacc[2] + lacc[3];
  l += __shfl_xor(l, 32);

  __syncthreads();  // all compute done; union switches to merge arrays
  // Merge kv-halves (plain add — no-max softmax has no rescale factor).
  if (kvh == 1) {
#pragma unroll
    for (int hb = 0; hb < 2; hb++)
#pragma unroll
      for (int r = 0; r < 16; r++) {
        const int hd = hb * 32 + (r & 3) + 8 * (r >> 2) + 4 * hi;
        sh.m.O[qg][hd][l31] = o[hb][r];
      }
    if (hi == 0) sh.m.L[qg][l31] = l;
  }
  __syncthreads();
  if (kvh == 0) {
#pragma unroll
    for (int hb = 0; hb < 2; hb++)
#pragma unroll
      for (int r = 0; r < 16; r++) {
        const int hd = hb * 32 + (r & 3) + 8 * (r >> 2) + 4 * hi;
        o[hb][r] += sh.m.O[qg][hd][l31];
      }
    l += sh.m.L[qg][l31];
    const float inv = 1.0f / l;
    __bf16* Ow = Og + (((size_t)b * Ss + qw) * Hh + h) * HD;
#pragma unroll
    for (int hb = 0; hb < 2; hb++)
#pragma unroll
      for (int g = 0; g < 4; g++) {
        const int hd = hb * 32 + g * 8 + 4 * hi;
        bf16x2 w0, w1;
        w0[0] = (__bf16)(o[hb][g * 4 + 0] * inv);
        w0[1] = (__bf16)(o[hb][g * 4 + 1] * inv);
        w1[0] = (__bf16)(o[hb][g * 4 + 2] * inv);
        w1[1] = (__bf16)(o[hb][g * 4 + 3] * inv);
        *(bf16x2*)(Ow + hd) = w0;
        *(bf16x2*)(Ow + hd + 2) = w1;
      }
  }
}

// ---------------------------------------------------------------------------
extern "C" void kernel_launch(void* const* d_in, const int* in_sizes, int n_in,
                              void* d_out, int out_size, void* d_ws,
                              size_t ws_size, hipStream_t stream) {
  if (ws_size < WS_NEED) return;

  __bf16* ws = (__bf16*)d_ws;
  const __bf16* hsC = ws + CAN_HS;
  const __bf16* WqC = ws + CAN_WQ;
  const __bf16* bqC = ws + CAN_BQ;
  const __bf16* WkC = ws + CAN_WK;
  const __bf16* bkC = ws + CAN_BK;
  const __bf16* WvC = ws + CAN_WV;
  const __bf16* bvC = ws + CAN_BV;
  const __bf16* WoC = ws + CAN_WO;
  const __bf16* boC = ws + CAN_BO;
  __bf16* Q = ws + CAN_END;
  __bf16* K = Q + TSZ;
  __bf16* V = K + TSZ;  // transposed layout [B,H,HD,S]
  __bf16* AW = V + TSZ;
  float* out = (float*)d_out;

  canon_kernel<<<2048, 256, 0, stream>>>(
      (const float*)d_in[0], (const float*)d_in[2], (const float*)d_in[3],
      (const float*)d_in[4], (const float*)d_in[5], (const float*)d_in[6],
      (const float*)d_in[7], (const float*)d_in[8], (const float*)d_in[9], ws);
  gemm_bt<0, __bf16><<<dim3(32, 24), 256, 0, stream>>>(
      hsC, WqC, WkC, WvC, bqC, bkC, bvC, Q, K, V);
  attn_fused<<<dim3(32, 32), 256, 0, stream>>>(Q, K, V, (const float*)d_in[1],
                                               AW);
  gemm_bt<1, float><<<dim3(32, 8), 256, 0, stream>>>(
      AW, WoC, WoC, WoC, boC, boC, boC, out, out, out);
}

// Round 5
// 231.939 us; speedup vs baseline: 1.1101x; 1.0190x over previous
//
#include <hip/hip_runtime.h>
#include <hip/hip_bf16.h>
#include <stdint.h>

// B=2, S=2048, D=1024, H=16, HD=64. Inputs fp32, d_out fp32 (resolved r1-r3).
// canon fp32->bf16 (+ mask*log2e -> bf16 stashed in d_out) -> QKV GEMM
// (Q pre-scaled by 0.125*log2e; V transposed [B,H,HD,S]) -> flash attn
// (32x32 MFMA, kv-split 2-way, no-max exp2 softmax) -> out-proj GEMM fp32
// (overwrites d_out last).
// r9: XOR-swizzled K/V LDS. r11: one-barrier+setprio (neutral).
// r12: mask staged via global_load_lds (attn 104->89us; gather was the stall).
// r13: (a) XCD-bijective block swizzle — each XCD owns 4 bh wholly, K/V
// working set 16MB->2MB per XCD (L2-resident staging); (b) mask bf16
// pre-scaled by log2e in canon, stored in d_out (16.78MB, exact fit;
// out-proj overwrites it later); (c) LDS 40KB -> 4 blocks/CU even packing.
#define Bb 2
#define Ss 2048
#define Dd 1024
#define Hh 16
#define HD 64

typedef __attribute__((ext_vector_type(8))) __bf16 bf16x8;
typedef __attribute__((ext_vector_type(4))) __bf16 bf16x4;
typedef __attribute__((ext_vector_type(2))) __bf16 bf16x2;
typedef __attribute__((ext_vector_type(4))) float f32x4;
typedef __attribute__((ext_vector_type(16))) float f32x16;

#define LOG2E 1.44269504088896f
#define SCL2 (0.125f * LOG2E)

// ---- workspace layout (bf16 elements) --------------------------------------
#define HS_N   (Bb * Ss * Dd)
#define W_N    (Dd * Dd)
#define B_N    (Dd)
#define MS_N   ((long)Bb * Ss * Ss)
#define CAN_HS 0
#define CAN_WQ (CAN_HS + HS_N)
#define CAN_BQ (CAN_WQ + W_N)
#define CAN_WK (CAN_BQ + B_N)
#define CAN_BK (CAN_WK + W_N)
#define CAN_WV (CAN_BK + B_N)
#define CAN_BV (CAN_WV + W_N)
#define CAN_WO (CAN_BV + B_N)
#define CAN_BO (CAN_WO + W_N)
#define CAN_END (CAN_BO + B_N)
#define TSZ    (Bb * Hh * Ss * HD)
#define WS_ELEMS (CAN_END + 4 * TSZ)
#define WS_NEED ((size_t)WS_ELEMS * 2)

__device__ __forceinline__ void gl_lds16(const __bf16* g, __bf16* l) {
  __builtin_amdgcn_global_load_lds(
      (const __attribute__((address_space(1))) void*)g,
      (__attribute__((address_space(3))) void*)l,
      16, 0, 0);
}

__device__ __forceinline__ void cfence() { asm volatile("" ::: "memory"); }

// fp32 -> bf16 canonicalization (segment table; r4 postmortem).
// r13: also emits mask*log2e as bf16 into mout (aliased to d_out).
__global__ void canon_kernel(const float* hs, const float* Wq, const float* bq,
                             const float* Wk, const float* bk, const float* Wv,
                             const float* bv, const float* Wo, const float* bo,
                             __bf16* __restrict__ dst,
                             const float* __restrict__ Mf,
                             __bf16* __restrict__ mout) {
  const float* srcs[9] = {hs, Wq, bq, Wk, bk, Wv, bv, Wo, bo};
  const long starts[10] = {CAN_HS, CAN_WQ, CAN_BQ, CAN_WK, CAN_BK,
                           CAN_WV, CAN_BV, CAN_WO, CAN_BO, CAN_END};
  const long nA = CAN_END / 8;
  const long nTot = nA + MS_N / 8;
  for (long c = blockIdx.x * blockDim.x + threadIdx.x; c < nTot;
       c += (long)gridDim.x * blockDim.x) {
    if (c < nA) {
      const long i = c * 8;
      int seg = 0;
#pragma unroll
      for (int t = 1; t < 9; t++) seg += (i >= starts[t]) ? 1 : 0;
      const float* s = srcs[seg] + (i - starts[seg]);
      bf16x8 v;
#pragma unroll
      for (int e = 0; e < 8; e++) v[e] = (__bf16)s[e];
      *(bf16x8*)(dst + i) = v;
    } else {
      const long i = (c - nA) * 8;
      const float* s = Mf + i;
      bf16x8 v;
#pragma unroll
      for (int e = 0; e < 8; e++) v[e] = (__bf16)(s[e] * LOG2E);
      *(bf16x8*)(mout + i) = v;
    }
  }
}

// ---------------------------------------------------------------------------
// GEMM: C[4096, 1024(x3)] = A @ W^T + bias (bf16 in).  (unchanged from r11)
// ---------------------------------------------------------------------------
template <int MODE, typename OutT>
__global__ __launch_bounds__(256, 2) void gemm_bt(
    const __bf16* __restrict__ A,
    const __bf16* __restrict__ W0, const __bf16* __restrict__ W1,
    const __bf16* __restrict__ W2,
    const __bf16* __restrict__ b0, const __bf16* __restrict__ b1,
    const __bf16* __restrict__ b2,
    OutT* __restrict__ O0, OutT* __restrict__ O1, OutT* __restrict__ O2) {
  __shared__ __align__(16) __bf16 sA[128 * 32 + 12544];  // pad -> 3 blk/CU
  __shared__ __align__(16) __bf16 sB[128 * 32];
  const int tid = threadIdx.x;
  const int lane = tid & 63;
  const int wid = tid >> 6;
  const int quad = lane >> 4;
  const int l15 = lane & 15;
  const int mBlock = blockIdx.x * 128;

  const __bf16* W;
  const __bf16* bias;
  OutT* Out;
  int nBlock, which = 0;
  if (MODE == 0) {
    which = blockIdx.y >> 3;  // 0:Q 1:K 2:V
    nBlock = (blockIdx.y & 7) * 128;
    W = which == 0 ? W0 : (which == 1 ? W1 : W2);
    bias = which == 0 ? b0 : (which == 1 ? b1 : b2);
    Out = which == 0 ? O0 : (which == 1 ? O1 : O2);
  } else {
    nBlock = blockIdx.y * 128;
    W = W0;
    bias = b0;
    Out = O0;
  }

  const int waveM = (wid >> 1) * 64;
  const int waveN = (wid & 1) * 64;

  f32x4 acc[4][4] = {};

  const int c1 = wid * 64 + lane;
  const int c2 = c1 + 256;
  const __bf16* Ar1 = A + (mBlock + (c1 >> 2)) * Dd + (c1 & 3) * 8;
  const __bf16* Ar2 = A + (mBlock + (c2 >> 2)) * Dd + (c2 & 3) * 8;
  const __bf16* Wr1 = W + (nBlock + (c1 >> 2)) * Dd + (c1 & 3) * 8;
  const __bf16* Wr2 = W + (nBlock + (c2 >> 2)) * Dd + (c2 & 3) * 8;
  __bf16* ldsA1 = sA + (wid * 64) * 8;
  __bf16* ldsA2 = sA + (wid * 64 + 256) * 8;
  __bf16* ldsB1 = sB + (wid * 64) * 8;
  __bf16* ldsB2 = sB + (wid * 64 + 256) * 8;

  for (int k0 = 0; k0 < Dd; k0 += 32) {
    gl_lds16(Ar1 + k0, ldsA1);
    gl_lds16(Ar2 + k0, ldsA2);
    gl_lds16(Wr1 + k0, ldsB1);
    gl_lds16(Wr2 + k0, ldsB2);
    __syncthreads();

    bf16x8 aF[4], bF[4];
#pragma unroll
    for (int mi = 0; mi < 4; mi++)
      aF[mi] = *(const bf16x8*)(sA + (waveM + mi * 16 + l15) * 32 + quad * 8);
#pragma unroll
    for (int ni = 0; ni < 4; ni++)
      bF[ni] = *(const bf16x8*)(sB + (waveN + ni * 16 + l15) * 32 + quad * 8);
#pragma unroll
    for (int mi = 0; mi < 4; mi++)
#pragma unroll
      for (int ni = 0; ni < 4; ni++)
        acc[mi][ni] = __builtin_amdgcn_mfma_f32_16x16x32_bf16(
            aF[mi], bF[ni], acc[mi][ni], 0, 0, 0);
    __syncthreads();
  }

  // C/D layout: col = lane&15, row = quad*4 + r.
#pragma unroll
  for (int ni = 0; ni < 4; ni++) {
    const int ng = nBlock + waveN + ni * 16 + l15;
    const float bv = (float)bias[ng];
#pragma unroll
    for (int mi = 0; mi < 4; mi++) {
      const int mg0 = mBlock + waveM + mi * 16 + quad * 4;
      if (MODE == 0 && which == 2) {
        const int b = mg0 >> 11, s0 = mg0 & 2047;
        const int h = ng >> 6, hd = ng & 63;
        bf16x4 pk;
#pragma unroll
        for (int r = 0; r < 4; r++) pk[r] = (__bf16)(acc[mi][ni][r] + bv);
        *(bf16x4*)((__bf16*)Out + (((b * Hh + h) * HD + hd) * Ss) + s0) = pk;
      } else {
#pragma unroll
        for (int r = 0; r < 4; r++) {
          float v = acc[mi][ni][r] + bv;
          const int m = mg0 + r;
          if (MODE == 0) {
            if (which == 0) v *= SCL2;  // fold softmax scale+log2e into Q
            const int b = m >> 11, s = m & 2047;
            const int h = ng >> 6, hd = ng & 63;
            Out[(((b * Hh + h) * Ss + s) * HD) + hd] = (OutT)v;
          } else {
            Out[m * Dd + ng] = (OutT)v;
          }
        }
      }
    }
  }
}

// ---------------------------------------------------------------------------
// Flash attention r13: 32x32 MFMA, kv-split 2-way, no-max softmax.
// Grid flattened to 1024; XCD-bijective decode: xcd = id&7 owns bh in
// {xcd, xcd+8, xcd+16, xcd+24} -> per-XCD K/V working set 2MB (L2-resident).
// Per iter: vmcnt(0) -> barrier A (tile i K/V+mask visible)
//   -> issue K/V stage(i+1) -> read mask(i) from LDS (ds_read_b64 x4)
//   -> lgkmcnt(0) -> barrier B -> issue mask stage(i+1) -> compute(i).
// LDS: kv[2][8KB K | 8KB V] (source-swizzled slots, r9) + mk 8KB bf16 mask
// (source-swizzled chunks, involution p8 = l8 ^ (row&7)). 40KB -> 4 blk/CU.
// Mask is PRE-SCALED by log2e (canon) -> C-init is a bare bf16->f32 cvt.
// ---------------------------------------------------------------------------
__global__ __launch_bounds__(256, 4) void attn_fused(
    const __bf16* __restrict__ Qg, const __bf16* __restrict__ Kg,
    const __bf16* __restrict__ Vt, const __bf16* __restrict__ Mbf,
    __bf16* __restrict__ Og) {
  __shared__ __align__(16) union {
    struct {
      __bf16 kv[2][8192];  // [buffer][K 4096 | V 4096]
      __bf16 mk[4096];     // mask tile 64q x 64kv bf16 (8 chunks/row)
    } s;
    struct {
      float O[2][64][32];  // [qg][hd][q] kv-half-1 partial
      float L[2][32];
    } m;
  } sh;

  const int tid = threadIdx.x;
  const int lane = tid & 63;
  const int wid = tid >> 6;
  const int qg = wid & 1;
  const int kvh = wid >> 1;
  const int l31 = lane & 31;
  const int hi = lane >> 5;

  // XCD-bijective decode (id&7 = XCD under round-robin dispatch).
  const int id = blockIdx.x;
  const int j = id >> 3;                 // [0,128)
  const int bh = (id & 7) + 8 * (j >> 5);  // [0,32): 4 bh per XCD
  const int qb0 = (j & 31) * 64;         // q-block
  const int b = bh >> 4;
  const int h = bh & 15;
  const int qw = qb0 + qg * 32 + l31;    // this lane's q row

  const __bf16* Qp = Qg + (size_t)bh * Ss * HD;
  const __bf16* Kp = Kg + (size_t)bh * Ss * HD;
  const __bf16* Vp = Vt + (size_t)bh * HD * Ss;  // [hd][S]
  const __bf16* Mb = Mbf + (size_t)b * Ss * Ss;  // bf16, pre-scaled log2e

  // Q B-fragments in registers (B[k=hd][n=q]; lane: hd = 16k + 8hi + j).
  bf16x8 qf[4];
#pragma unroll
  for (int k = 0; k < 4; k++)
    qf[k] = *(const bf16x8*)(Qp + (size_t)qw * HD + k * 16 + hi * 8);

  const int cA = tid, cB = 256 + tid;
  // K/V staging (r9-proven): linear LDS dest, source carries the slot
  // swizzle ((row>>1)&3).
#define STAGE_KV(BI, KVS)                                                     \
  {                                                                           \
    const int rwA = (cA & 255) >> 2, rwB = (cB & 255) >> 2;                   \
    const int slA = (cA & 3) ^ ((rwA >> 1) & 3);                              \
    const int slB = (cB & 3) ^ ((rwB >> 1) & 3);                              \
    __bf16* kb = sh.s.kv[BI];                                                 \
    gl_lds16(Kp + ((KVS) + rwA) * HD + (cA >> 8) * 32 + slA * 8, kb + cA * 8);\
    gl_lds16(Kp + ((KVS) + rwB) * HD + (cB >> 8) * 32 + slB * 8, kb + cB * 8);\
    __bf16* vb = sh.s.kv[BI] + 4096;                                          \
    gl_lds16(Vp + (size_t)rwA * Ss + (KVS) + (cA >> 8) * 32 + slA * 8,        \
             vb + cA * 8);                                                    \
    gl_lds16(Vp + (size_t)rwB * Ss + (KVS) + (cB >> 8) * 32 + slB * 8,        \
             vb + cB * 8);                                                    \
  }

  // Mask staging: 512 16B-chunks (8 bf16 each), 2 per thread. Chunk c lands
  // linearly at slot c = row mq (c>>3) x phys8 (c&7); source fetches logical
  // chunk l8 = (c&7) ^ (mq&7) so the read-side XOR is an involution.
  // 8 consecutive threads fetch one full 128B row (coalesced).
#define STAGE_M(KVS)                                                          \
  {                                                                           \
    _Pragma("unroll")                                                         \
    for (int rr = 0; rr < 2; rr++) {                                          \
      const int c = tid + rr * 256;                                           \
      const int mq = c >> 3;                                                  \
      const int l8 = (c & 7) ^ (mq & 7);                                      \
      gl_lds16(Mb + (size_t)(qb0 + mq) * Ss + (KVS) + l8 * 8,                 \
               sh.s.mk + c * 8);                                              \
    }                                                                         \
  }

  f32x16 o[2] = {};  // O^T partials: row=hd (C-layout), col=q
  f32x4 lacc = {0.f, 0.f, 0.f, 0.f};

  const int rsw = (l31 >> 1) & 3;  // K/V read-side slot XOR (row>>1)&3

  // Prologue: tile 0 K/V + mask(0) staged.
  STAGE_KV(0, 0);
  STAGE_M(0);

  for (int it = 0; it < 32; ++it) {
    const int bufc = it & 1;
    cfence();
    asm volatile("s_waitcnt vmcnt(0)" ::: "memory");  // drain stage(it)
    cfence();
    __builtin_amdgcn_s_barrier();  // A: tile-i K/V + mask visible
    cfence();
    if (it < 31) {
      STAGE_KV(bufc ^ 1, (it + 1) * 64);  // K/V prefetch overlaps everything
      cfence();
    }

    // Read mask(i) tile from LDS: lane wants row mq = qg*32+l31,
    // kv = 32kvh + 8g + 4hi + r -> logical chunk l8 = 4kvh + g,
    // phys8 = l8 ^ (mq&7), within-chunk offset 4hi.
    bf16x4 mcv[4];
    const int mq = qg * 32 + l31;
#pragma unroll
    for (int g = 0; g < 4; g++) {
      const int p8 = (4 * kvh + g) ^ (l31 & 7);
      mcv[g] = *(const bf16x4*)(sh.s.mk + mq * 64 + p8 * 8 + 4 * hi);
    }
    cfence();
    asm volatile("s_waitcnt lgkmcnt(0)" ::: "memory");  // mask reads done
    cfence();
    __builtin_amdgcn_s_barrier();  // B: all waves consumed mask(i)
    cfence();
    if (it < 31) {
      STAGE_M((it + 1) * 64);  // safe to overwrite mask tile now
      cfence();
    }

    // S^T = K Q^T with C-init = mask (already *log2e; layout: reg g*4+r <->
    // kv = 8g+4hi+r, col q = l31).
    f32x16 sacc;
#pragma unroll
    for (int g = 0; g < 4; g++)
#pragma unroll
      for (int r = 0; r < 4; r++) sacc[g * 4 + r] = (float)mcv[g][r];
    __builtin_amdgcn_s_setprio(1);
#pragma unroll
    for (int k = 0; k < 4; k++) {
      const int ps = (((k & 1) << 1) | hi) ^ rsw;  // swizzled slot
      bf16x8 kf = *(const bf16x8*)(sh.s.kv[bufc] +
                                   ((k >> 1) * 64 + kvh * 32 + l31) * 32 +
                                   ps * 8);
      sacc = __builtin_amdgcn_mfma_f32_32x32x16_bf16(kf, qf[k], sacc, 0, 0, 0);
    }
    __builtin_amdgcn_s_setprio(0);

    // p = exp2(s); row-sum into lacc.
    f32x4 sv[4];
#pragma unroll
    for (int g = 0; g < 4; g++)
#pragma unroll
      for (int r = 0; r < 4; r++)
        sv[g][r] = __builtin_amdgcn_exp2f(sacc[g * 4 + r]);
    lacc += (sv[0] + sv[1]) + (sv[2] + sv[3]);

    // P^T B-fragments via register exchange (r9-proven):
    // B-frag needs kv = ks*16 + 8hi + e; lane holds kv = 8g + 4hi + r.
    // hi=0 sends g1,g3 / receives partner g0,g2; hi=1 symmetric.
    bf16x4 pk[4];
#pragma unroll
    for (int g = 0; g < 4; g++)
#pragma unroll
      for (int r = 0; r < 4; r++) pk[g][r] = (__bf16)sv[g][r];
    union pu { bf16x4 v; uint32_t w[2]; };
    pu s0, s1, r0, r1;
    s0.v = hi ? pk[0] : pk[1];
    s1.v = hi ? pk[2] : pk[3];
    r0.w[0] = __shfl_xor((int)s0.w[0], 32);
    r0.w[1] = __shfl_xor((int)s0.w[1], 32);
    r1.w[0] = __shfl_xor((int)s1.w[0], 32);
    r1.w[1] = __shfl_xor((int)s1.w[1], 32);
    bf16x8 pf[2];
    {
      bf16x4 lo0 = hi ? r0.v : pk[0], hi0 = hi ? pk[1] : r0.v;
      bf16x4 lo1 = hi ? r1.v : pk[2], hi1 = hi ? pk[3] : r1.v;
#pragma unroll
      for (int e = 0; e < 4; e++) {
        pf[0][e] = lo0[e]; pf[0][e + 4] = hi0[e];
        pf[1][e] = lo1[e]; pf[1][e + 4] = hi1[e];
      }
    }

    // O^T += V^T P^T (contraction over wave's kv 32: 2 ksteps).
    __builtin_amdgcn_s_setprio(1);
#pragma unroll
    for (int k = 0; k < 2; k++)
#pragma unroll
      for (int hb = 0; hb < 2; hb++) {
        const int ps = ((k << 1) | hi) ^ rsw;  // swizzled slot
        bf16x8 vf = *(const bf16x8*)(sh.s.kv[bufc] + 4096 +
                                     (kvh * 64 + hb * 32 + l31) * 32 +
                                     ps * 8);
        o[hb] = __builtin_amdgcn_mfma_f32_32x32x16_bf16(vf, pf[k], o[hb],
                                                        0, 0, 0);
      }
    __builtin_amdgcn_s_setprio(0);
  }

  float l = lacc[0] + lacc[1] + lacc[2] + lacc[3];
  l += __shfl_xor(l, 32);

  __syncthreads();  // all compute done; union switches to merge arrays
  // Merge kv-halves (plain add — no-max softmax has no rescale factor).
  if (kvh == 1) {
#pragma unroll
    for (int hb = 0; hb < 2; hb++)
#pragma unroll
      for (int r = 0; r < 16; r++) {
        const int hd = hb * 32 + (r & 3) + 8 * (r >> 2) + 4 * hi;
        sh.m.O[qg][hd][l31] = o[hb][r];
      }
    if (hi == 0) sh.m.L[qg][l31] = l;
  }
  __syncthreads();
  if (kvh == 0) {
#pragma unroll
    for (int hb = 0; hb < 2; hb++)
#pragma unroll
      for (int r = 0; r < 16; r++) {
        const int hd = hb * 32 + (r & 3) + 8 * (r >> 2) + 4 * hi;
        o[hb][r] += sh.m.O[qg][hd][l31];
      }
    l += sh.m.L[qg][l31];
    const float inv = 1.0f / l;
    __bf16* Ow = Og + (((size_t)b * Ss + qw) * Hh + h) * HD;
#pragma unroll
    for (int hb = 0; hb < 2; hb++)
#pragma unroll
      for (int g = 0; g < 4; g++) {
        const int hd = hb * 32 + g * 8 + 4 * hi;
        bf16x2 w0, w1;
        w0[0] = (__bf16)(o[hb][g * 4 + 0] * inv);
        w0[1] = (__bf16)(o[hb][g * 4 + 1] * inv);
        w1[0] = (__bf16)(o[hb][g * 4 + 2] * inv);
        w1[1] = (__bf16)(o[hb][g * 4 + 3] * inv);
        *(bf16x2*)(Ow + hd) = w0;
        *(bf16x2*)(Ow + hd + 2) = w1;
      }
  }
}

// ---------------------------------------------------------------------------
extern "C" void kernel_launch(void* const* d_in, const int* in_sizes, int n_in,
                              void* d_out, int out_size, void* d_ws,
                              size_t ws_size, hipStream_t stream) {
  if (ws_size < WS_NEED) return;

  __bf16* ws = (__bf16*)d_ws;
  const __bf16* hsC = ws + CAN_HS;
  const __bf16* WqC = ws + CAN_WQ;
  const __bf16* bqC = ws + CAN_BQ;
  const __bf16* WkC = ws + CAN_WK;
  const __bf16* bkC = ws + CAN_BK;
  const __bf16* WvC = ws + CAN_WV;
  const __bf16* bvC = ws + CAN_BV;
  const __bf16* WoC = ws + CAN_WO;
  const __bf16* boC = ws + CAN_BO;
  __bf16* Q = ws + CAN_END;
  __bf16* K = Q + TSZ;
  __bf16* V = K + TSZ;  // transposed layout [B,H,HD,S]
  __bf16* AW = V + TSZ;
  float* out = (float*)d_out;
  // bf16 mask (pre-scaled by log2e) lives in d_out until out-proj overwrites
  // it: B*S*S bf16 = 16.78MB = B*S*D fp32 exactly.
  __bf16* Mbf = (__bf16*)d_out;

  canon_kernel<<<2048, 256, 0, stream>>>(
      (const float*)d_in[0], (const float*)d_in[2], (const float*)d_in[3],
      (const float*)d_in[4], (const float*)d_in[5], (const float*)d_in[6],
      (const float*)d_in[7], (const float*)d_in[8], (const float*)d_in[9], ws,
      (const float*)d_in[1], Mbf);
  gemm_bt<0, __bf16><<<dim3(32, 24), 256, 0, stream>>>(
      hsC, WqC, WkC, WvC, bqC, bkC, bvC, Q, K, V);
  attn_fused<<<dim3(1024), 256, 0, stream>>>(Q, K, V, Mbf, AW);
  gemm_bt<1, float><<<dim3(32, 8), 256, 0, stream>>>(
      AW, WoC, WoC, WoC, boC, boC, boC, out, out, out);
}

// Round 6
// 224.964 us; speedup vs baseline: 1.1446x; 1.0310x over previous
//
#include <hip/hip_runtime.h>
#include <hip/hip_bf16.h>
#include <stdint.h>

// B=2, S=2048, D=1024, H=16, HD=64. Inputs fp32, d_out fp32 (resolved r1-r3).
// canon fp32->bf16 (+ mask*log2e -> bf16 stashed in d_out) -> QKV GEMM
// (Q pre-scaled by 0.125*log2e; V transposed [B,H,HD,S]) -> flash attn
// (32x32 MFMA, kv-split 2-way, no-max exp2 softmax) -> out-proj GEMM fp32.
// r12: mask staged via global_load_lds (attn 104->89us; gather was the stall).
// r13: XCD decode + mask bf16 in d_out + 40KB LDS/4 blk-CU (89->69us).
// r14: (a) P-exchange via v_permlane32_swap_b32 — semantics (vdst.hi<->src.lo)
// isolated by the r10-fail/r11-pass differential; pf[ks]={a'0,a'1,b'0,b'1}
// uniform across halves, no divergent selects, no shfl ds ops. (b) XCD decode
// b-partitioned: XCD x owns bh {4x..4x+3} so each XCD streams only one
// batch's mask through L2.
#define Bb 2
#define Ss 2048
#define Dd 1024
#define Hh 16
#define HD 64

typedef __attribute__((ext_vector_type(8))) __bf16 bf16x8;
typedef __attribute__((ext_vector_type(4))) __bf16 bf16x4;
typedef __attribute__((ext_vector_type(2))) __bf16 bf16x2;
typedef __attribute__((ext_vector_type(4))) float f32x4;
typedef __attribute__((ext_vector_type(16))) float f32x16;

#define LOG2E 1.44269504088896f
#define SCL2 (0.125f * LOG2E)

// ---- workspace layout (bf16 elements) --------------------------------------
#define HS_N   (Bb * Ss * Dd)
#define W_N    (Dd * Dd)
#define B_N    (Dd)
#define MS_N   ((long)Bb * Ss * Ss)
#define CAN_HS 0
#define CAN_WQ (CAN_HS + HS_N)
#define CAN_BQ (CAN_WQ + W_N)
#define CAN_WK (CAN_BQ + B_N)
#define CAN_BK (CAN_WK + W_N)
#define CAN_WV (CAN_BK + B_N)
#define CAN_BV (CAN_WV + W_N)
#define CAN_WO (CAN_BV + B_N)
#define CAN_BO (CAN_WO + W_N)
#define CAN_END (CAN_BO + B_N)
#define TSZ    (Bb * Hh * Ss * HD)
#define WS_ELEMS (CAN_END + 4 * TSZ)
#define WS_NEED ((size_t)WS_ELEMS * 2)

__device__ __forceinline__ void gl_lds16(const __bf16* g, __bf16* l) {
  __builtin_amdgcn_global_load_lds(
      (const __attribute__((address_space(1))) void*)g,
      (__attribute__((address_space(3))) void*)l,
      16, 0, 0);
}

__device__ __forceinline__ void cfence() { asm volatile("" ::: "memory"); }

// fp32 -> bf16 canonicalization (segment table; r4 postmortem).
// r13: also emits mask*log2e as bf16 into mout (aliased to d_out).
__global__ void canon_kernel(const float* hs, const float* Wq, const float* bq,
                             const float* Wk, const float* bk, const float* Wv,
                             const float* bv, const float* Wo, const float* bo,
                             __bf16* __restrict__ dst,
                             const float* __restrict__ Mf,
                             __bf16* __restrict__ mout) {
  const float* srcs[9] = {hs, Wq, bq, Wk, bk, Wv, bv, Wo, bo};
  const long starts[10] = {CAN_HS, CAN_WQ, CAN_BQ, CAN_WK, CAN_BK,
                           CAN_WV, CAN_BV, CAN_WO, CAN_BO, CAN_END};
  const long nA = CAN_END / 8;
  const long nTot = nA + MS_N / 8;
  for (long c = blockIdx.x * blockDim.x + threadIdx.x; c < nTot;
       c += (long)gridDim.x * blockDim.x) {
    if (c < nA) {
      const long i = c * 8;
      int seg = 0;
#pragma unroll
      for (int t = 1; t < 9; t++) seg += (i >= starts[t]) ? 1 : 0;
      const float* s = srcs[seg] + (i - starts[seg]);
      bf16x8 v;
#pragma unroll
      for (int e = 0; e < 8; e++) v[e] = (__bf16)s[e];
      *(bf16x8*)(dst + i) = v;
    } else {
      const long i = (c - nA) * 8;
      const float* s = Mf + i;
      bf16x8 v;
#pragma unroll
      for (int e = 0; e < 8; e++) v[e] = (__bf16)(s[e] * LOG2E);
      *(bf16x8*)(mout + i) = v;
    }
  }
}

// ---------------------------------------------------------------------------
// GEMM: C[4096, 1024(x3)] = A @ W^T + bias (bf16 in).  (unchanged from r11)
// ---------------------------------------------------------------------------
template <int MODE, typename OutT>
__global__ __launch_bounds__(256, 2) void gemm_bt(
    const __bf16* __restrict__ A,
    const __bf16* __restrict__ W0, const __bf16* __restrict__ W1,
    const __bf16* __restrict__ W2,
    const __bf16* __restrict__ b0, const __bf16* __restrict__ b1,
    const __bf16* __restrict__ b2,
    OutT* __restrict__ O0, OutT* __restrict__ O1, OutT* __restrict__ O2) {
  __shared__ __align__(16) __bf16 sA[128 * 32 + 12544];  // pad -> 3 blk/CU
  __shared__ __align__(16) __bf16 sB[128 * 32];
  const int tid = threadIdx.x;
  const int lane = tid & 63;
  const int wid = tid >> 6;
  const int quad = lane >> 4;
  const int l15 = lane & 15;
  const int mBlock = blockIdx.x * 128;

  const __bf16* W;
  const __bf16* bias;
  OutT* Out;
  int nBlock, which = 0;
  if (MODE == 0) {
    which = blockIdx.y >> 3;  // 0:Q 1:K 2:V
    nBlock = (blockIdx.y & 7) * 128;
    W = which == 0 ? W0 : (which == 1 ? W1 : W2);
    bias = which == 0 ? b0 : (which == 1 ? b1 : b2);
    Out = which == 0 ? O0 : (which == 1 ? O1 : O2);
  } else {
    nBlock = blockIdx.y * 128;
    W = W0;
    bias = b0;
    Out = O0;
  }

  const int waveM = (wid >> 1) * 64;
  const int waveN = (wid & 1) * 64;

  f32x4 acc[4][4] = {};

  const int c1 = wid * 64 + lane;
  const int c2 = c1 + 256;
  const __bf16* Ar1 = A + (mBlock + (c1 >> 2)) * Dd + (c1 & 3) * 8;
  const __bf16* Ar2 = A + (mBlock + (c2 >> 2)) * Dd + (c2 & 3) * 8;
  const __bf16* Wr1 = W + (nBlock + (c1 >> 2)) * Dd + (c1 & 3) * 8;
  const __bf16* Wr2 = W + (nBlock + (c2 >> 2)) * Dd + (c2 & 3) * 8;
  __bf16* ldsA1 = sA + (wid * 64) * 8;
  __bf16* ldsA2 = sA + (wid * 64 + 256) * 8;
  __bf16* ldsB1 = sB + (wid * 64) * 8;
  __bf16* ldsB2 = sB + (wid * 64 + 256) * 8;

  for (int k0 = 0; k0 < Dd; k0 += 32) {
    gl_lds16(Ar1 + k0, ldsA1);
    gl_lds16(Ar2 + k0, ldsA2);
    gl_lds16(Wr1 + k0, ldsB1);
    gl_lds16(Wr2 + k0, ldsB2);
    __syncthreads();

    bf16x8 aF[4], bF[4];
#pragma unroll
    for (int mi = 0; mi < 4; mi++)
      aF[mi] = *(const bf16x8*)(sA + (waveM + mi * 16 + l15) * 32 + quad * 8);
#pragma unroll
    for (int ni = 0; ni < 4; ni++)
      bF[ni] = *(const bf16x8*)(sB + (waveN + ni * 16 + l15) * 32 + quad * 8);
#pragma unroll
    for (int mi = 0; mi < 4; mi++)
#pragma unroll
      for (int ni = 0; ni < 4; ni++)
        acc[mi][ni] = __builtin_amdgcn_mfma_f32_16x16x32_bf16(
            aF[mi], bF[ni], acc[mi][ni], 0, 0, 0);
    __syncthreads();
  }

  // C/D layout: col = lane&15, row = quad*4 + r.
#pragma unroll
  for (int ni = 0; ni < 4; ni++) {
    const int ng = nBlock + waveN + ni * 16 + l15;
    const float bv = (float)bias[ng];
#pragma unroll
    for (int mi = 0; mi < 4; mi++) {
      const int mg0 = mBlock + waveM + mi * 16 + quad * 4;
      if (MODE == 0 && which == 2) {
        const int b = mg0 >> 11, s0 = mg0 & 2047;
        const int h = ng >> 6, hd = ng & 63;
        bf16x4 pk;
#pragma unroll
        for (int r = 0; r < 4; r++) pk[r] = (__bf16)(acc[mi][ni][r] + bv);
        *(bf16x4*)((__bf16*)Out + (((b * Hh + h) * HD + hd) * Ss) + s0) = pk;
      } else {
#pragma unroll
        for (int r = 0; r < 4; r++) {
          float v = acc[mi][ni][r] + bv;
          const int m = mg0 + r;
          if (MODE == 0) {
            if (which == 0) v *= SCL2;  // fold softmax scale+log2e into Q
            const int b = m >> 11, s = m & 2047;
            const int h = ng >> 6, hd = ng & 63;
            Out[(((b * Hh + h) * Ss + s) * HD) + hd] = (OutT)v;
          } else {
            Out[m * Dd + ng] = (OutT)v;
          }
        }
      }
    }
  }
}

// ---------------------------------------------------------------------------
// Flash attention r14: 32x32 MFMA, kv-split 2-way, no-max softmax.
// Grid 1024 flat; b-partitioned XCD decode: XCD x = id&7 owns bh {4x..4x+3}
// (b uniform per XCD -> each XCD streams only ONE batch's mask via L2).
// Per iter: vmcnt(0) -> barrier A (tile i K/V+mask visible)
//   -> issue K/V stage(i+1) -> read mask(i) from LDS -> lgkmcnt(0)
//   -> barrier B -> issue mask stage(i+1) -> compute(i).
// LDS: kv[2][8KB K | 8KB V] (source-swizzled slots, r9) + mk 8KB bf16 mask
// (source-swizzled chunks, involution p8 = l8 ^ (row&7)). 40KB -> 4 blk/CU.
// P-exchange: v_permlane32_swap_b32 (vdst.hi <-> src.lo — isolated by the
// r10-fail/r11-pass differential): (a',b') = swap(a=pk[2ks].w, b=pk[2ks+1].w)
// -> pf[ks] = {a'0,a'1,b'0,b'1} valid for BOTH lane halves (no selects).
// ---------------------------------------------------------------------------
__global__ __launch_bounds__(256, 4) void attn_fused(
    const __bf16* __restrict__ Qg, const __bf16* __restrict__ Kg,
    const __bf16* __restrict__ Vt, const __bf16* __restrict__ Mbf,
    __bf16* __restrict__ Og) {
  __shared__ __align__(16) union {
    struct {
      __bf16 kv[2][8192];  // [buffer][K 4096 | V 4096]
      __bf16 mk[4096];     // mask tile 64q x 64kv bf16 (8 chunks/row)
    } s;
    struct {
      float O[2][64][32];  // [qg][hd][q] kv-half-1 partial
      float L[2][32];
    } m;
  } sh;

  const int tid = threadIdx.x;
  const int lane = tid & 63;
  const int wid = tid >> 6;
  const int qg = wid & 1;
  const int kvh = wid >> 1;
  const int l31 = lane & 31;
  const int hi = lane >> 5;

  // b-partitioned XCD-bijective decode (id&7 = XCD under round-robin).
  const int id = blockIdx.x;
  const int j = id >> 3;                   // [0,128)
  const int bh = (id & 7) * 4 + (j >> 5);  // XCD x owns bh {4x..4x+3}
  const int qb0 = (j & 31) * 64;           // q-block
  const int b = bh >> 4;
  const int h = bh & 15;
  const int qw = qb0 + qg * 32 + l31;      // this lane's q row

  const __bf16* Qp = Qg + (size_t)bh * Ss * HD;
  const __bf16* Kp = Kg + (size_t)bh * Ss * HD;
  const __bf16* Vp = Vt + (size_t)bh * HD * Ss;  // [hd][S]
  const __bf16* Mb = Mbf + (size_t)b * Ss * Ss;  // bf16, pre-scaled log2e

  // Q B-fragments in registers (B[k=hd][n=q]; lane: hd = 16k + 8hi + j).
  bf16x8 qf[4];
#pragma unroll
  for (int k = 0; k < 4; k++)
    qf[k] = *(const bf16x8*)(Qp + (size_t)qw * HD + k * 16 + hi * 8);

  const int cA = tid, cB = 256 + tid;
  // K/V staging (r9-proven): linear LDS dest, source carries the slot
  // swizzle ((row>>1)&3).
#define STAGE_KV(BI, KVS)                                                     \
  {                                                                           \
    const int rwA = (cA & 255) >> 2, rwB = (cB & 255) >> 2;                   \
    const int slA = (cA & 3) ^ ((rwA >> 1) & 3);                              \
    const int slB = (cB & 3) ^ ((rwB >> 1) & 3);                              \
    __bf16* kb = sh.s.kv[BI];                                                 \
    gl_lds16(Kp + ((KVS) + rwA) * HD + (cA >> 8) * 32 + slA * 8, kb + cA * 8);\
    gl_lds16(Kp + ((KVS) + rwB) * HD + (cB >> 8) * 32 + slB * 8, kb + cB * 8);\
    __bf16* vb = sh.s.kv[BI] + 4096;                                          \
    gl_lds16(Vp + (size_t)rwA * Ss + (KVS) + (cA >> 8) * 32 + slA * 8,        \
             vb + cA * 8);                                                    \
    gl_lds16(Vp + (size_t)rwB * Ss + (KVS) + (cB >> 8) * 32 + slB * 8,        \
             vb + cB * 8);                                                    \
  }

  // Mask staging: 512 16B-chunks (8 bf16 each), 2 per thread. Chunk c lands
  // linearly at slot c = row mq (c>>3) x phys8 (c&7); source fetches logical
  // chunk l8 = (c&7) ^ (mq&7) so the read-side XOR is an involution.
#define STAGE_M(KVS)                                                          \
  {                                                                           \
    _Pragma("unroll")                                                         \
    for (int rr = 0; rr < 2; rr++) {                                          \
      const int c = tid + rr * 256;                                           \
      const int mq = c >> 3;                                                  \
      const int l8 = (c & 7) ^ (mq & 7);                                      \
      gl_lds16(Mb + (size_t)(qb0 + mq) * Ss + (KVS) + l8 * 8,                 \
               sh.s.mk + c * 8);                                              \
    }                                                                         \
  }

  f32x16 o[2] = {};  // O^T partials: row=hd (C-layout), col=q
  f32x4 lacc = {0.f, 0.f, 0.f, 0.f};

  const int rsw = (l31 >> 1) & 3;  // K/V read-side slot XOR (row>>1)&3

  // Prologue: tile 0 K/V + mask(0) staged.
  STAGE_KV(0, 0);
  STAGE_M(0);

  for (int it = 0; it < 32; ++it) {
    const int bufc = it & 1;
    cfence();
    asm volatile("s_waitcnt vmcnt(0)" ::: "memory");  // drain stage(it)
    cfence();
    __builtin_amdgcn_s_barrier();  // A: tile-i K/V + mask visible
    cfence();
    if (it < 31) {
      STAGE_KV(bufc ^ 1, (it + 1) * 64);  // K/V prefetch overlaps everything
      cfence();
    }

    // Read mask(i) tile from LDS: lane wants row mq = qg*32+l31,
    // kv = 32kvh + 8g + 4hi + r -> logical chunk l8 = 4kvh + g,
    // phys8 = l8 ^ (mq&7), within-chunk offset 4hi.
    bf16x4 mcv[4];
    const int mq = qg * 32 + l31;
#pragma unroll
    for (int g = 0; g < 4; g++) {
      const int p8 = (4 * kvh + g) ^ (l31 & 7);
      mcv[g] = *(const bf16x4*)(sh.s.mk + mq * 64 + p8 * 8 + 4 * hi);
    }
    cfence();
    asm volatile("s_waitcnt lgkmcnt(0)" ::: "memory");  // mask reads done
    cfence();
    __builtin_amdgcn_s_barrier();  // B: all waves consumed mask(i)
    cfence();
    if (it < 31) {
      STAGE_M((it + 1) * 64);  // safe to overwrite mask tile now
      cfence();
    }

    // S^T = K Q^T with C-init = mask (already *log2e; layout: reg g*4+r <->
    // kv = 8g+4hi+r, col q = l31).
    f32x16 sacc;
#pragma unroll
    for (int g = 0; g < 4; g++)
#pragma unroll
      for (int r = 0; r < 4; r++) sacc[g * 4 + r] = (float)mcv[g][r];
    __builtin_amdgcn_s_setprio(1);
#pragma unroll
    for (int k = 0; k < 4; k++) {
      const int ps = (((k & 1) << 1) | hi) ^ rsw;  // swizzled slot
      bf16x8 kf = *(const bf16x8*)(sh.s.kv[bufc] +
                                   ((k >> 1) * 64 + kvh * 32 + l31) * 32 +
                                   ps * 8);
      sacc = __builtin_amdgcn_mfma_f32_32x32x16_bf16(kf, qf[k], sacc, 0, 0, 0);
    }
    __builtin_amdgcn_s_setprio(0);

    // p = exp2(s); row-sum into lacc.
    f32x4 sv[4];
#pragma unroll
    for (int g = 0; g < 4; g++)
#pragma unroll
      for (int r = 0; r < 4; r++)
        sv[g][r] = __builtin_amdgcn_exp2f(sacc[g * 4 + r]);
    lacc += (sv[0] + sv[1]) + (sv[2] + sv[3]);

    // P^T B-fragments via v_permlane32_swap_b32.
    // Lane (q=l31, half h) holds pk[g] with kv = 8g+4h+r; B-frag pf[ks]
    // element e <-> kv = 16ks + 8h + e.  e0..3 live in h'=0's pk[2ks+h'...]:
    // derivation: e0..3 = pk[2ks+h] of h'=0 lane, e4..7 = pk[2ks+h] of h'=1
    // lane. With swap semantics vdst.hi <-> src.lo:
    //   (a',b') = swap(a = pk[2ks].w, b = pk[2ks+1].w)
    //   a' = {lo: own pk[2ks], hi: partner-lo pk[2ks+1]}
    //   b' = {lo: partner-hi pk[2ks], hi: own pk[2ks+1]}
    // -> pf[ks] = {a'0, a'1, b'0, b'1} for BOTH halves (checked per-half).
    union pu { bf16x4 v; uint32_t w[2]; };
    pu pk[4];
#pragma unroll
    for (int g = 0; g < 4; g++)
#pragma unroll
      for (int r = 0; r < 4; r++) pk[g].v[r] = (__bf16)sv[g][r];
    union PF { bf16x8 v; uint32_t u[4]; } pf[2];
#pragma unroll
    for (int ks = 0; ks < 2; ks++) {
      uint32_t a0 = pk[2 * ks].w[0], b0 = pk[2 * ks + 1].w[0];
      uint32_t a1 = pk[2 * ks].w[1], b1 = pk[2 * ks + 1].w[1];
      asm volatile("s_nop 1\n\tv_permlane32_swap_b32 %0, %1"
                   : "+v"(a0), "+v"(b0));
      asm volatile("s_nop 1\n\tv_permlane32_swap_b32 %0, %1"
                   : "+v"(a1), "+v"(b1));
      pf[ks].u[0] = a0;
      pf[ks].u[1] = a1;
      pf[ks].u[2] = b0;
      pf[ks].u[3] = b1;
    }

    // O^T += V^T P^T (contraction over wave's kv 32: 2 ksteps).
    __builtin_amdgcn_s_setprio(1);
#pragma unroll
    for (int k = 0; k < 2; k++)
#pragma unroll
      for (int hb = 0; hb < 2; hb++) {
        const int ps = ((k << 1) | hi) ^ rsw;  // swizzled slot
        bf16x8 vf = *(const bf16x8*)(sh.s.kv[bufc] + 4096 +
                                     (kvh * 64 + hb * 32 + l31) * 32 +
                                     ps * 8);
        o[hb] = __builtin_amdgcn_mfma_f32_32x32x16_bf16(vf, pf[k].v, o[hb],
                                                        0, 0, 0);
      }
    __builtin_amdgcn_s_setprio(0);
  }

  float l = lacc[0] + lacc[1] + lacc[2] + lacc[3];
  l += __shfl_xor(l, 32);

  __syncthreads();  // all compute done; union switches to merge arrays
  // Merge kv-halves (plain add — no-max softmax has no rescale factor).
  if (kvh == 1) {
#pragma unroll
    for (int hb = 0; hb < 2; hb++)
#pragma unroll
      for (int r = 0; r < 16; r++) {
        const int hd = hb * 32 + (r & 3) + 8 * (r >> 2) + 4 * hi;
        sh.m.O[qg][hd][l31] = o[hb][r];
      }
    if (hi == 0) sh.m.L[qg][l31] = l;
  }
  __syncthreads();
  if (kvh == 0) {
#pragma unroll
    for (int hb = 0; hb < 2; hb++)
#pragma unroll
      for (int r = 0; r < 16; r++) {
        const int hd = hb * 32 + (r & 3) + 8 * (r >> 2) + 4 * hi;
        o[hb][r] += sh.m.O[qg][hd][l31];
      }
    l += sh.m.L[qg][l31];
    const float inv = 1.0f / l;
    __bf16* Ow = Og + (((size_t)b * Ss + qw) * Hh + h) * HD;
#pragma unroll
    for (int hb = 0; hb < 2; hb++)
#pragma unroll
      for (int g = 0; g < 4; g++) {
        const int hd = hb * 32 + g * 8 + 4 * hi;
        bf16x2 w0, w1;
        w0[0] = (__bf16)(o[hb][g * 4 + 0] * inv);
        w0[1] = (__bf16)(o[hb][g * 4 + 1] * inv);
        w1[0] = (__bf16)(o[hb][g * 4 + 2] * inv);
        w1[1] = (__bf16)(o[hb][g * 4 + 3] * inv);
        *(bf16x2*)(Ow + hd) = w0;
        *(bf16x2*)(Ow + hd + 2) = w1;
      }
  }
}

// ---------------------------------------------------------------------------
extern "C" void kernel_launch(void* const* d_in, const int* in_sizes, int n_in,
                              void* d_out, int out_size, void* d_ws,
                              size_t ws_size, hipStream_t stream) {
  if (ws_size < WS_NEED) return;

  __bf16* ws = (__bf16*)d_ws;
  const __bf16* hsC = ws + CAN_HS;
  const __bf16* WqC = ws + CAN_WQ;
  const __bf16* bqC = ws + CAN_BQ;
  const __bf16* WkC = ws + CAN_WK;
  const __bf16* bkC = ws + CAN_BK;
  const __bf16* WvC = ws + CAN_WV;
  const __bf16* bvC = ws + CAN_BV;
  const __bf16* WoC = ws + CAN_WO;
  const __bf16* boC = ws + CAN_BO;
  __bf16* Q = ws + CAN_END;
  __bf16* K = Q + TSZ;
  __bf16* V = K + TSZ;  // transposed layout [B,H,HD,S]
  __bf16* AW = V + TSZ;
  float* out = (float*)d_out;
  // bf16 mask (pre-scaled by log2e) lives in d_out until out-proj overwrites
  // it: B*S*S bf16 = 16.78MB = B*S*D fp32 exactly.
  __bf16* Mbf = (__bf16*)d_out;

  canon_kernel<<<2048, 256, 0, stream>>>(
      (const float*)d_in[0], (const float*)d_in[2], (const float*)d_in[3],
      (const float*)d_in[4], (const float*)d_in[5], (const float*)d_in[6],
      (const float*)d_in[7], (const float*)d_in[8], (const float*)d_in[9], ws,
      (const float*)d_in[1], Mbf);
  gemm_bt<0, __bf16><<<dim3(32, 24), 256, 0, stream>>>(
      hsC, WqC, WkC, WvC, bqC, bkC, bvC, Q, K, V);
  attn_fused<<<dim3(1024), 256, 0, stream>>>(Q, K, V, Mbf, AW);
  gemm_bt<1, float><<<dim3(32, 8), 256, 0, stream>>>(
      AW, WoC, WoC, WoC, boC, boC, boC, out, out, out);
}